// Round 6
// baseline (348.206 us; speedup 1.0000x reference)
//
#include <hip/hip_runtime.h>
#include <hip/hip_bf16.h>

#define DHID 64
typedef __attribute__((ext_vector_type(8))) short short8;
typedef __attribute__((ext_vector_type(4))) float f32x4;

static __device__ __forceinline__ short tobf(float f) {
  __hip_bfloat16 h = __float2bfloat16(f);
  return *reinterpret_cast<short*>(&h);
}
static __device__ __forceinline__ float frombf(short s) {
  union { unsigned u; float f; } v; v.u = ((unsigned)(unsigned short)s) << 16; return v.f;
}
// which XCD this block is physically on (0..7) — HW-verified readable (m09)
static __device__ __forceinline__ int xcc_id() {
  unsigned v;
  asm volatile("s_getreg_b32 %0, hwreg(HW_REG_XCC_ID)" : "=s"(v));
  return (int)(v & 7);
}

// ---------- CSR build ----------
__global__ void k_init(int* __restrict__ cnt, int* __restrict__ fill,
                       int* __restrict__ bcnt, int* __restrict__ wq, int n) {
  int i = blockIdx.x * blockDim.x + threadIdx.x;
  if (i < n) { cnt[i] = 1; fill[i] = 0; }  // cnt=1 pre-counts the self-loop
  if (i < 8) bcnt[i] = 0;
  if (i < 16) wq[i] = 0;
}

// one-pass 8-way partition of edges by dst window (block-local LDS histogram,
// one global atomic per window per block). Buckets live in the xb/hb region
// (dead until after CSR build).
__global__ void k_bucket(const int* __restrict__ src, const int* __restrict__ dst,
                         int2* __restrict__ bkt, int* __restrict__ bcnt,
                         int E, int N, int cap) {
  __shared__ int lcnt[8];
  __shared__ int lbase[8];
  int tid = threadIdx.x;
  int c0 = blockIdx.x * 2048;
  if (c0 >= E) return;
  if (tid < 8) lcnt[tid] = 0;
  __syncthreads();
  float inv = 8.0f / (float)N;
  int wloc[8], dloc[8], sloc[8];
  #pragma unroll
  for (int k = 0; k < 8; k++) {
    int i = c0 + tid + k * 256;
    if (i < E) {
      int d = dst[i];
      int w = min(7, (int)((float)d * inv));
      wloc[k] = w; dloc[k] = d; sloc[k] = src[i];
      atomicAdd(&lcnt[w], 1);
    } else wloc[k] = -1;
  }
  __syncthreads();
  if (tid < 8) lbase[tid] = atomicAdd(&bcnt[tid], lcnt[tid]);
  __syncthreads();
  if (tid < 8) lcnt[tid] = 0;  // reuse as local rank counter
  __syncthreads();
  #pragma unroll
  for (int k = 0; k < 8; k++) {
    int w = wloc[k];
    if (w >= 0) {
      int r = atomicAdd(&lcnt[w], 1);
      bkt[(size_t)w * cap + lbase[w] + r] = make_int2(sloc[k], dloc[k]);
    }
  }
}

// XCC-pinned histogram: block serves ONLY the window matching its physical XCD;
// chunks handed out by a per-window atomic queue (self-balancing). All cnt[]
// lines for window w stay in XCD w's L2.
#define CSR_CHUNK 4096
__global__ void k_hist3(const int2* __restrict__ bkt, const int* __restrict__ bcnt,
                        int* __restrict__ wq, int* __restrict__ cnt, int cap) {
  __shared__ int sbase;
  int w = xcc_id();
  int n = bcnt[w];
  const int2* b = bkt + (size_t)w * cap;
  for (;;) {
    if (threadIdx.x == 0) sbase = atomicAdd(&wq[w], CSR_CHUNK);
    __syncthreads();
    int base = sbase;
    __syncthreads();
    if (base >= n) return;
    int end = min(base + CSR_CHUNK, n);
    for (int i = base + threadIdx.x; i < end; i += blockDim.x)
      atomicAdd(&cnt[b[i].y], 1);
  }
}

__global__ void k_scan_block(int* __restrict__ buf, int n, int* __restrict__ bsum) {
  __shared__ int lds[256];
  int tid = threadIdx.x;
  int base = blockIdx.x * 1024 + tid * 4;
  int a0 = (base + 0) < n ? buf[base + 0] : 0;
  int a1 = (base + 1) < n ? buf[base + 1] : 0;
  int a2 = (base + 2) < n ? buf[base + 2] : 0;
  int a3 = (base + 3) < n ? buf[base + 3] : 0;
  int s = a0 + a1 + a2 + a3;
  lds[tid] = s; __syncthreads();
  for (int off = 1; off < 256; off <<= 1) {
    int t = (tid >= off) ? lds[tid - off] : 0;
    __syncthreads();
    lds[tid] += t;
    __syncthreads();
  }
  int excl = lds[tid] - s;
  if ((base + 0) < n) buf[base + 0] = excl; excl += a0;
  if ((base + 1) < n) buf[base + 1] = excl; excl += a1;
  if ((base + 2) < n) buf[base + 2] = excl; excl += a2;
  if ((base + 3) < n) buf[base + 3] = excl;
  if (tid == 255) bsum[blockIdx.x] = lds[255];
}

__global__ void k_scan_mid(int* __restrict__ bsum, int nb) {
  int lane = threadIdx.x;
  int v0 = (lane < nb) ? bsum[lane] : 0;
  #pragma unroll
  for (int off = 1; off < 64; off <<= 1) { int t = __shfl_up(v0, off, 64); if (lane >= off) v0 += t; }
  int v1 = (64 + lane) < nb ? bsum[64 + lane] : 0;
  #pragma unroll
  for (int off = 1; off < 64; off <<= 1) { int t = __shfl_up(v1, off, 64); if (lane >= off) v1 += t; }
  v1 += __shfl(v0, 63, 64);
  if (lane < nb) bsum[lane] = v0;
  if ((64 + lane) < nb) bsum[64 + lane] = v1;
}

__global__ void k_scan_add(int* __restrict__ buf, int n, const int* __restrict__ bsum, int nb) {
  int i = blockIdx.x * blockDim.x + threadIdx.x;
  if (i < n) { int c = i >> 10; if (c > 0) buf[i] += bsum[c - 1]; }
  if (i == 0) buf[n] = bsum[nb - 1];
}

// deterministic self-loop placement: reserved last slot of each row
__global__ void k_self(const int* __restrict__ roff, int* __restrict__ csr, int N) {
  int i = blockIdx.x * blockDim.x + threadIdx.x;
  if (i < N) csr[roff[i + 1] - 1] = i;
}

// XCC-pinned CSR fill (same scheme as k_hist3; queue slots 8..15)
__global__ void k_fill3(const int2* __restrict__ bkt, const int* __restrict__ bcnt,
                        int* __restrict__ wq, const int* __restrict__ roff,
                        int* __restrict__ fill, int* __restrict__ csr, int cap) {
  __shared__ int sbase;
  int w = xcc_id();
  int n = bcnt[w];
  const int2* b = bkt + (size_t)w * cap;
  for (;;) {
    if (threadIdx.x == 0) sbase = atomicAdd(&wq[8 + w], CSR_CHUNK);
    __syncthreads();
    int base = sbase;
    __syncthreads();
    if (base >= n) return;
    int end = min(base + CSR_CHUNK, n);
    for (int i = base + threadIdx.x; i < end; i += blockDim.x) {
      int2 e = b[i];
      int pos = roff[e.y] + atomicAdd(&fill[e.y], 1);
      csr[pos] = e.x;
    }
  }
}

// ---------- prep: x fp32 -> bf16, XOR-swizzled rows (K=128) ----------
__global__ void k_cvt(const float* __restrict__ x, short* __restrict__ xb, int N) {
  int i = blockIdx.x * blockDim.x + threadIdx.x;   // one 8-elem chunk
  int tot = N * 16;
  if (i >= tot) return;
  int row = i >> 4;
  int kc = (i & 15) << 3;
  const float4* xp = (const float4*)(x + (size_t)row * 128 + kc);
  float4 v0 = xp[0], v1 = xp[1];
  short8 o;
  o[0] = tobf(v0.x); o[1] = tobf(v0.y); o[2] = tobf(v0.z); o[3] = tobf(v0.w);
  o[4] = tobf(v1.x); o[5] = tobf(v1.y); o[6] = tobf(v1.z); o[7] = tobf(v1.w);
  int ks = kc ^ ((row & 7) << 3);
  *(short8*)(xb + (size_t)row * 128 + ks) = o;
}

// ---------- prep: W [K][64] -> Wt bf16 [64][K], XOR-swizzled ----------
__global__ void k_prep(const float* __restrict__ W, short* __restrict__ wt, int K) {
  for (int e = threadIdx.x; e < 64 * K; e += blockDim.x) {
    int c = e / K, k = e - c * K;
    wt[c * K + (k ^ ((c & 7) << 3))] = tobf(W[k * 64 + c]);
  }
}

// ---------- MFMA gemm: hb[n][d] = xb[n][:] @ Wt[d][:]^T ; + as/ad dots ----------
template<int K>
__launch_bounds__(256)
__global__ void k_mgemm(const short* __restrict__ xb, const short* __restrict__ wt,
                        const float* __restrict__ a_s, const float* __restrict__ a_d,
                        short* __restrict__ hb, float* __restrict__ asb,
                        float* __restrict__ adb, int N) {
  constexpr int ASZ = 64 * K * 2;          // bytes of A tile (== B tile)
  __shared__ __align__(16) short lds[2 * 64 * K];
  int tid = threadIdx.x;
  int n0 = blockIdx.x * 64;

  const char* ga = (const char*)xb + (size_t)n0 * (K * 2);
  const char* gb = (const char*)wt;
  #pragma unroll
  for (int j = 0; j < (2 * ASZ) / 4096; j++) {
    int d = j * 4096 + tid * 16;
    const char* src = (d < ASZ) ? (ga + d) : (gb + (d - ASZ));
    __builtin_amdgcn_global_load_lds(
        (__attribute__((address_space(1))) const void*)src,
        (__attribute__((address_space(3))) void*)((char*)lds + d), 16, 0, 0);
  }
  __syncthreads();

  int l = tid & 63, w = tid >> 6;
  int c = l & 15, g = l >> 4;
  const short* A = lds;
  const short* B = lds + 64 * K;
  f32x4 acc[4];
  #pragma unroll
  for (int t = 0; t < 4; t++) acc[t] = (f32x4){0.f, 0.f, 0.f, 0.f};

  int arow = 16 * w + c;
  #pragma unroll
  for (int s = 0; s < K / 32; s++) {
    int ke = s * 32 + g * 8;
    short8 af = *(const short8*)(A + arow * K + (ke ^ ((arow & 7) << 3)));
    #pragma unroll
    for (int t = 0; t < 4; t++) {
      int bcol = 16 * t + c;
      short8 bf = *(const short8*)(B + bcol * K + (ke ^ ((bcol & 7) << 3)));
      acc[t] = __builtin_amdgcn_mfma_f32_16x16x32_bf16(af, bf, acc[t], 0, 0, 0);
    }
  }

  float av_s[4], av_d[4];
  #pragma unroll
  for (int t = 0; t < 4; t++) { av_s[t] = a_s[16 * t + c]; av_d[t] = a_d[16 * t + c]; }
  #pragma unroll
  for (int q = 0; q < 4; q++) {
    int row = n0 + 16 * w + g * 4 + q;
    bool ok = row < N;
    float rs = 0.f, rd = 0.f;
    #pragma unroll
    for (int t = 0; t < 4; t++) {
      float v = acc[t][q];
      if (ok) hb[(size_t)row * 64 + 16 * t + c] = tobf(v);
      rs += v * av_s[t]; rd += v * av_d[t];
    }
    #pragma unroll
    for (int off = 1; off < 16; off <<= 1) {
      rs += __shfl_xor(rs, off, 64);
      rd += __shfl_xor(rd, off, 64);
    }
    if (ok && c == 0) { asb[row] = rs; adb[row] = rd; }
  }
}

// ---------- sparse: fused softmax + aggregation, one wave per dst node ----------
__global__ void k_agg(const int* __restrict__ roff, const int* __restrict__ csr,
                      const float* __restrict__ asb, const float* __restrict__ adb,
                      const short* __restrict__ hb, const float* __restrict__ b,
                      float* __restrict__ out, short* __restrict__ outb,
                      int N, int relu) {
  int lane = threadIdx.x & 63;
  int wid = blockIdx.x * (blockDim.x >> 6) + (threadIdx.x >> 6);
  int nw = gridDim.x * (blockDim.x >> 6);
  float bv = b[lane];
  for (int n = wid; n < N; n += nw) {
    int r0 = roff[n], r1 = roff[n + 1];
    float adn = adb[n];
    float acc = 0.f, denl = 0.f;
    for (int base = r0; base < r1; base += 64) {
      int cnt = min(64, r1 - base);
      int s = 0; float e = 0.f;
      if (lane < cnt) {
        s = csr[base + lane];
        float l = asb[s] + adn;
        l = fmaxf(l, 0.2f * l);
        e = __expf(l);
      }
      denl += e;
      for (int j = 0; j < cnt; j += 8) {
        #pragma unroll
        for (int k = 0; k < 8; k++) {
          int   sk = __builtin_amdgcn_readlane(s, j + k);
          float ek = __uint_as_float(__builtin_amdgcn_readlane(__float_as_uint(e), j + k));
          acc += ek * frombf(hb[(size_t)sk * DHID + lane]);
        }
      }
    }
    float den = denl;
    #pragma unroll
    for (int off = 32; off; off >>= 1) den += __shfl_xor(den, off, 64);
    float o = acc / (den + 1e-16f) + bv;
    if (relu) o = fmaxf(o, 0.f);
    out[(size_t)n * DHID + lane] = o;
    if (outb) outb[(size_t)n * DHID + (lane ^ ((n & 7) << 3))] = tobf(o);
  }
}

extern "C" void kernel_launch(void* const* d_in, const int* in_sizes, int n_in,
                              void* d_out, int out_size, void* d_ws, size_t ws_size,
                              hipStream_t stream) {
  const float* x   = (const float*)d_in[0];
  const int*   ei  = (const int*)d_in[1];
  const float* W1  = (const float*)d_in[2];
  const float* as1 = (const float*)d_in[3];
  const float* ad1 = (const float*)d_in[4];
  const float* b1  = (const float*)d_in[5];
  const float* W2  = (const float*)d_in[6];
  const float* as2 = (const float*)d_in[7];
  const float* ad2 = (const float*)d_in[8];
  const float* b2  = (const float*)d_in[9];

  int N = in_sizes[0] / 128;
  int E = in_sizes[1] / 2;
  const int* srcp = ei;
  const int* dstp = ei + E;

  float* emb  = (float*)d_out;
  float* out2 = emb + (size_t)N * DHID;

  char* w = (char*)d_ws;
  auto alloc = [&](size_t bytes) { char* p = w; w += (bytes + 255) & ~(size_t)255; return p; };
  int NR = ((N + 63) / 64) * 64;
  int* roff = (int*)alloc((size_t)(N + 1) * 4);
  int* fill = (int*)alloc((size_t)N * 4);
  int* csr  = (int*)alloc((size_t)(E + N) * 4);
  int* bsum = (int*)alloc(2048);
  int* wq   = (int*)alloc(64);
  short* xb = (short*)alloc((size_t)NR * 128 * 2);
  short* hb = (short*)alloc((size_t)NR * 64 * 2);
  float* asb = (float*)alloc((size_t)N * 4);
  float* adb = (float*)alloc((size_t)N * 4);
  short* wt1 = (short*)alloc(64 * 128 * 2);
  short* wt2 = (short*)alloc(64 * 64 * 2);
  short* eb = xb;                 // overlay: xb dead after mgemm1
  int2* bkt = (int2*)xb;          // overlay: buckets dead before k_cvt writes xb
  int* bcnt = (int*)hb;           // overlay: hb dead until mgemm1
  int cap = E / 8 + 65536;

  int nb = (N + 1023) / 1024;
  int NBLK = (N + 63) / 64;

  k_init<<<(N + 255) / 256, 256, 0, stream>>>(roff, fill, bcnt, wq, N);
  k_bucket<<<(E + 2047) / 2048, 256, 0, stream>>>(srcp, dstp, bkt, bcnt, E, N, cap);
  k_hist3<<<1024, 256, 0, stream>>>(bkt, bcnt, wq, roff, cap);
  k_scan_block<<<nb, 256, 0, stream>>>(roff, N, bsum);
  k_scan_mid<<<1, 64, 0, stream>>>(bsum, nb);
  k_scan_add<<<(N + 255) / 256, 256, 0, stream>>>(roff, N, bsum, nb);
  k_self<<<(N + 255) / 256, 256, 0, stream>>>(roff, csr, N);
  k_fill3<<<1024, 256, 0, stream>>>(bkt, bcnt, wq, roff, fill, csr, cap);

  // buckets now dead -> safe to overwrite xb/hb
  k_prep<<<1, 256, 0, stream>>>(W1, wt1, 128);
  k_prep<<<1, 256, 0, stream>>>(W2, wt2, 64);
  k_cvt<<<(N * 16 + 255) / 256, 256, 0, stream>>>(x, xb, N);

  k_mgemm<128><<<NBLK, 256, 0, stream>>>(xb, wt1, as1, ad1, hb, asb, adb, N);
  k_agg<<<2048, 256, 0, stream>>>(roff, csr, asb, adb, hb, b1, emb, eb, N, 1);
  k_mgemm<64><<<NBLK, 256, 0, stream>>>(eb, wt2, as2, ad2, hb, asb, adb, N);
  k_agg<<<2048, 256, 0, stream>>>(roff, csr, asb, adb, hb, b2, out2, (short*)nullptr, N, 0);
}

// Round 7
// 257.877 us; speedup vs baseline: 1.3503x; 1.3503x over previous
//
#include <hip/hip_runtime.h>
#include <hip/hip_bf16.h>

#define DHID 64
#define SUBSH 9
#define SUBSZ (1 << SUBSH)     // 512 dst nodes per sub-bucket
#define PCAP 16384             // LDS staging cap (ints) in k_place
typedef __attribute__((ext_vector_type(8))) short short8;
typedef __attribute__((ext_vector_type(4))) float f32x4;

static __device__ __forceinline__ short tobf(float f) {
  __hip_bfloat16 h = __float2bfloat16(f);
  return *reinterpret_cast<short*>(&h);
}
static __device__ __forceinline__ float frombf(short s) {
  union { unsigned u; float f; } v; v.u = ((unsigned)(unsigned short)s) << 16; return v.f;
}

// ---------- CSR build ----------
__global__ void k_init(int* __restrict__ cnt, int* __restrict__ bcnt, int n, int nsb) {
  int i = blockIdx.x * blockDim.x + threadIdx.x;
  if (i < n) cnt[i] = 1;          // pre-count self-loop (also reserves rank 0)
  if (i < nsb) bcnt[i] = 0;
}

// One streaming pass: per-edge in-rank via atomic (fused histogram), then
// partition (src, dlow|rank<<9) into 512-node dst sub-buckets. Bucket appends
// are block-contiguous runs -> coalesce; csr itself is never random-stored.
__global__ void k_bucket_rank(const int* __restrict__ src, const int* __restrict__ dst,
                              int* __restrict__ cnt, int2* __restrict__ bkt,
                              int* __restrict__ bcnt, int E, int nsb, int cap) {
  __shared__ int lcnt[256];
  __shared__ int lbase[256];
  int tid = threadIdx.x;
  int c0 = blockIdx.x * 2048;
  if (c0 >= E) return;
  for (int i = tid; i < nsb; i += 256) lcnt[i] = 0;
  __syncthreads();
  int wloc[8], yloc[8], sloc[8];
  #pragma unroll
  for (int k = 0; k < 8; k++) {
    int i = c0 + tid + k * 256;
    if (i < E) {
      int d = dst[i];
      int rk = atomicAdd(&cnt[d], 1);          // rank >= 1 (0 = self-loop)
      int w = d >> SUBSH;
      wloc[k] = w;
      yloc[k] = (d & (SUBSZ - 1)) | (rk << SUBSH);
      sloc[k] = src[i];
      atomicAdd(&lcnt[w], 1);
    } else wloc[k] = -1;
  }
  __syncthreads();
  for (int i = tid; i < nsb; i += 256) lbase[i] = atomicAdd(&bcnt[i], lcnt[i]);
  __syncthreads();
  for (int i = tid; i < nsb; i += 256) lcnt[i] = 0;   // reuse as local rank
  __syncthreads();
  #pragma unroll
  for (int k = 0; k < 8; k++) {
    int w = wloc[k];
    if (w >= 0) {
      int r = atomicAdd(&lcnt[w], 1);
      bkt[(size_t)w * cap + lbase[w] + r] = make_int2(sloc[k], yloc[k]);
    }
  }
}

__global__ void k_scan_block(int* __restrict__ buf, int n, int* __restrict__ bsum) {
  __shared__ int lds[256];
  int tid = threadIdx.x;
  int base = blockIdx.x * 1024 + tid * 4;
  int a0 = (base + 0) < n ? buf[base + 0] : 0;
  int a1 = (base + 1) < n ? buf[base + 1] : 0;
  int a2 = (base + 2) < n ? buf[base + 2] : 0;
  int a3 = (base + 3) < n ? buf[base + 3] : 0;
  int s = a0 + a1 + a2 + a3;
  lds[tid] = s; __syncthreads();
  for (int off = 1; off < 256; off <<= 1) {
    int t = (tid >= off) ? lds[tid - off] : 0;
    __syncthreads();
    lds[tid] += t;
    __syncthreads();
  }
  int excl = lds[tid] - s;
  if ((base + 0) < n) buf[base + 0] = excl; excl += a0;
  if ((base + 1) < n) buf[base + 1] = excl; excl += a1;
  if ((base + 2) < n) buf[base + 2] = excl; excl += a2;
  if ((base + 3) < n) buf[base + 3] = excl;
  if (tid == 255) bsum[blockIdx.x] = lds[255];
}

__global__ void k_scan_mid(int* __restrict__ bsum, int nb) {
  int lane = threadIdx.x;
  int v0 = (lane < nb) ? bsum[lane] : 0;
  #pragma unroll
  for (int off = 1; off < 64; off <<= 1) { int t = __shfl_up(v0, off, 64); if (lane >= off) v0 += t; }
  int v1 = (64 + lane) < nb ? bsum[64 + lane] : 0;
  #pragma unroll
  for (int off = 1; off < 64; off <<= 1) { int t = __shfl_up(v1, off, 64); if (lane >= off) v1 += t; }
  v1 += __shfl(v0, 63, 64);
  if (lane < nb) bsum[lane] = v0;
  if ((64 + lane) < nb) bsum[64 + lane] = v1;
}

__global__ void k_scan_add(int* __restrict__ buf, int n, const int* __restrict__ bsum, int nb) {
  int i = blockIdx.x * blockDim.x + threadIdx.x;
  if (i < n) { int c = i >> 10; if (c > 0) buf[i] += bsum[c - 1]; }
  if (i == 0) buf[n] = bsum[nb - 1];
}

// One block per sub-bucket: LDS counting-sort placement, then a single
// coalesced streaming write of the window's contiguous csr span.
__global__ void k_place(const int2* __restrict__ bkt, const int* __restrict__ bcnt,
                        const int* __restrict__ roff, int* __restrict__ csr,
                        int N, int cap) {
  __shared__ int roff_l[SUBSZ + 1];
  __shared__ int stage[PCAP];
  int sb = blockIdx.x, tid = threadIdx.x;
  int d0 = sb << SUBSH;
  int d1 = min(N, d0 + SUBSZ);
  int nn = d1 - d0;
  for (int j = tid; j <= nn; j += 256) roff_l[j] = roff[d0 + j];
  __syncthreads();
  int base = roff_l[0];
  int span = roff_l[nn] - base;
  int nE = bcnt[sb];
  const int2* b = bkt + (size_t)sb * cap;
  if (span <= PCAP) {
    for (int d = tid; d < nn; d += 256) stage[roff_l[d] - base] = d0 + d;  // self-loop @ rank 0
    for (int i = tid; i < nE; i += 256) {
      int2 e = b[i];
      stage[roff_l[e.y & (SUBSZ - 1)] - base + (e.y >> SUBSH)] = e.x;
    }
    __syncthreads();
    for (int j = tid; j < span; j += 256) csr[base + j] = stage[j];
  } else {  // statistically never for random graphs; correctness fallback
    for (int d = tid; d < nn; d += 256) csr[roff_l[d]] = d0 + d;
    for (int i = tid; i < nE; i += 256) {
      int2 e = b[i];
      csr[roff_l[e.y & (SUBSZ - 1)] + (e.y >> SUBSH)] = e.x;
    }
  }
}

// ---------- prep: x fp32 -> bf16, XOR-swizzled rows (K=128) ----------
__global__ void k_cvt(const float* __restrict__ x, short* __restrict__ xb, int N) {
  int i = blockIdx.x * blockDim.x + threadIdx.x;   // one 8-elem chunk
  int tot = N * 16;
  if (i >= tot) return;
  int row = i >> 4;
  int kc = (i & 15) << 3;
  const float4* xp = (const float4*)(x + (size_t)row * 128 + kc);
  float4 v0 = xp[0], v1 = xp[1];
  short8 o;
  o[0] = tobf(v0.x); o[1] = tobf(v0.y); o[2] = tobf(v0.z); o[3] = tobf(v0.w);
  o[4] = tobf(v1.x); o[5] = tobf(v1.y); o[6] = tobf(v1.z); o[7] = tobf(v1.w);
  int ks = kc ^ ((row & 7) << 3);
  *(short8*)(xb + (size_t)row * 128 + ks) = o;
}

// ---------- prep: W [K][64] -> Wt bf16 [64][K], XOR-swizzled ----------
__global__ void k_prep(const float* __restrict__ W, short* __restrict__ wt, int K) {
  for (int e = threadIdx.x; e < 64 * K; e += blockDim.x) {
    int c = e / K, k = e - c * K;
    wt[c * K + (k ^ ((c & 7) << 3))] = tobf(W[k * 64 + c]);
  }
}

// ---------- MFMA gemm: hb[n][d] = xb[n][:] @ Wt[d][:]^T ; + as/ad dots ----------
template<int K>
__launch_bounds__(256)
__global__ void k_mgemm(const short* __restrict__ xb, const short* __restrict__ wt,
                        const float* __restrict__ a_s, const float* __restrict__ a_d,
                        short* __restrict__ hb, float* __restrict__ asb,
                        float* __restrict__ adb, int N) {
  constexpr int ASZ = 64 * K * 2;          // bytes of A tile (== B tile)
  __shared__ __align__(16) short lds[2 * 64 * K];
  int tid = threadIdx.x;
  int n0 = blockIdx.x * 64;

  const char* ga = (const char*)xb + (size_t)n0 * (K * 2);
  const char* gb = (const char*)wt;
  #pragma unroll
  for (int j = 0; j < (2 * ASZ) / 4096; j++) {
    int d = j * 4096 + tid * 16;
    const char* src = (d < ASZ) ? (ga + d) : (gb + (d - ASZ));
    __builtin_amdgcn_global_load_lds(
        (__attribute__((address_space(1))) const void*)src,
        (__attribute__((address_space(3))) void*)((char*)lds + d), 16, 0, 0);
  }
  __syncthreads();

  int l = tid & 63, w = tid >> 6;
  int c = l & 15, g = l >> 4;
  const short* A = lds;
  const short* B = lds + 64 * K;
  f32x4 acc[4];
  #pragma unroll
  for (int t = 0; t < 4; t++) acc[t] = (f32x4){0.f, 0.f, 0.f, 0.f};

  int arow = 16 * w + c;
  #pragma unroll
  for (int s = 0; s < K / 32; s++) {
    int ke = s * 32 + g * 8;
    short8 af = *(const short8*)(A + arow * K + (ke ^ ((arow & 7) << 3)));
    #pragma unroll
    for (int t = 0; t < 4; t++) {
      int bcol = 16 * t + c;
      short8 bf = *(const short8*)(B + bcol * K + (ke ^ ((bcol & 7) << 3)));
      acc[t] = __builtin_amdgcn_mfma_f32_16x16x32_bf16(af, bf, acc[t], 0, 0, 0);
    }
  }

  float av_s[4], av_d[4];
  #pragma unroll
  for (int t = 0; t < 4; t++) { av_s[t] = a_s[16 * t + c]; av_d[t] = a_d[16 * t + c]; }
  #pragma unroll
  for (int q = 0; q < 4; q++) {
    int row = n0 + 16 * w + g * 4 + q;
    bool ok = row < N;
    float rs = 0.f, rd = 0.f;
    #pragma unroll
    for (int t = 0; t < 4; t++) {
      float v = acc[t][q];
      if (ok) hb[(size_t)row * 64 + 16 * t + c] = tobf(v);
      rs += v * av_s[t]; rd += v * av_d[t];
    }
    #pragma unroll
    for (int off = 1; off < 16; off <<= 1) {
      rs += __shfl_xor(rs, off, 64);
      rd += __shfl_xor(rd, off, 64);
    }
    if (ok && c == 0) { asb[row] = rs; adb[row] = rd; }
  }
}

// ---------- sparse: fused softmax + aggregation, one wave per dst node ----------
__global__ void k_agg(const int* __restrict__ roff, const int* __restrict__ csr,
                      const float* __restrict__ asb, const float* __restrict__ adb,
                      const short* __restrict__ hb, const float* __restrict__ b,
                      float* __restrict__ out, short* __restrict__ outb,
                      int N, int relu) {
  int lane = threadIdx.x & 63;
  int wid = blockIdx.x * (blockDim.x >> 6) + (threadIdx.x >> 6);
  int nw = gridDim.x * (blockDim.x >> 6);
  float bv = b[lane];
  for (int n = wid; n < N; n += nw) {
    int r0 = roff[n], r1 = roff[n + 1];
    float adn = adb[n];
    float acc = 0.f, denl = 0.f;
    for (int base = r0; base < r1; base += 64) {
      int cnt = min(64, r1 - base);
      int s = 0; float e = 0.f;
      if (lane < cnt) {
        s = csr[base + lane];
        float l = asb[s] + adn;
        l = fmaxf(l, 0.2f * l);
        e = __expf(l);
      }
      denl += e;
      for (int j = 0; j < cnt; j += 8) {
        #pragma unroll
        for (int k = 0; k < 8; k++) {
          int   sk = __builtin_amdgcn_readlane(s, j + k);
          float ek = __uint_as_float(__builtin_amdgcn_readlane(__float_as_uint(e), j + k));
          acc += ek * frombf(hb[(size_t)sk * DHID + lane]);
        }
      }
    }
    float den = denl;
    #pragma unroll
    for (int off = 32; off; off >>= 1) den += __shfl_xor(den, off, 64);
    float o = acc / (den + 1e-16f) + bv;
    if (relu) o = fmaxf(o, 0.f);
    out[(size_t)n * DHID + lane] = o;
    if (outb) outb[(size_t)n * DHID + (lane ^ ((n & 7) << 3))] = tobf(o);
  }
}

extern "C" void kernel_launch(void* const* d_in, const int* in_sizes, int n_in,
                              void* d_out, int out_size, void* d_ws, size_t ws_size,
                              hipStream_t stream) {
  const float* x   = (const float*)d_in[0];
  const int*   ei  = (const int*)d_in[1];
  const float* W1  = (const float*)d_in[2];
  const float* as1 = (const float*)d_in[3];
  const float* ad1 = (const float*)d_in[4];
  const float* b1  = (const float*)d_in[5];
  const float* W2  = (const float*)d_in[6];
  const float* as2 = (const float*)d_in[7];
  const float* ad2 = (const float*)d_in[8];
  const float* b2  = (const float*)d_in[9];

  int N = in_sizes[0] / 128;
  int E = in_sizes[1] / 2;
  const int* srcp = ei;
  const int* dstp = ei + E;

  float* emb  = (float*)d_out;
  float* out2 = emb + (size_t)N * DHID;

  char* w = (char*)d_ws;
  auto alloc = [&](size_t bytes) { char* p = w; w += (bytes + 255) & ~(size_t)255; return p; };
  int NR = ((N + 63) / 64) * 64;
  int* roff = (int*)alloc((size_t)(N + 1) * 4);
  int* csr  = (int*)alloc((size_t)(E + N) * 4);
  int* bsum = (int*)alloc(2048);
  short* xb = (short*)alloc((size_t)NR * 128 * 2);
  short* hb = (short*)alloc((size_t)NR * 64 * 2);
  float* asb = (float*)alloc((size_t)N * 4);
  float* adb = (float*)alloc((size_t)N * 4);
  short* wt1 = (short*)alloc(64 * 128 * 2);
  short* wt2 = (short*)alloc(64 * 64 * 2);
  short* eb = xb;                 // overlay: xb dead after mgemm1
  int2* bkt = (int2*)xb;          // overlay: buckets dead before k_cvt writes xb
  int* bcnt = (int*)hb;           // overlay: hb dead until mgemm1

  int nsb = (N + SUBSZ - 1) >> SUBSH;          // 196 sub-buckets
  int cap = E / nsb + 4096;                    // per-sub-bucket capacity (int2)

  int nb = (N + 1023) / 1024;
  int NBLK = (N + 63) / 64;

  k_init<<<(N + 255) / 256, 256, 0, stream>>>(roff, bcnt, N, nsb);
  k_bucket_rank<<<(E + 2047) / 2048, 256, 0, stream>>>(srcp, dstp, roff, bkt, bcnt, E, nsb, cap);
  k_scan_block<<<nb, 256, 0, stream>>>(roff, N, bsum);
  k_scan_mid<<<1, 64, 0, stream>>>(bsum, nb);
  k_scan_add<<<(N + 255) / 256, 256, 0, stream>>>(roff, N, bsum, nb);
  k_place<<<nsb, 256, 0, stream>>>(bkt, bcnt, roff, csr, N, cap);

  // buckets now dead -> safe to overwrite xb/hb
  k_prep<<<1, 256, 0, stream>>>(W1, wt1, 128);
  k_prep<<<1, 256, 0, stream>>>(W2, wt2, 64);
  k_cvt<<<(N * 16 + 255) / 256, 256, 0, stream>>>(x, xb, N);

  k_mgemm<128><<<NBLK, 256, 0, stream>>>(xb, wt1, as1, ad1, hb, asb, adb, N);
  k_agg<<<2048, 256, 0, stream>>>(roff, csr, asb, adb, hb, b1, emb, eb, N, 1);
  k_mgemm<64><<<NBLK, 256, 0, stream>>>(eb, wt2, as2, ad2, hb, asb, adb, N);
  k_agg<<<2048, 256, 0, stream>>>(roff, csr, asb, adb, hb, b2, out2, (short*)nullptr, N, 0);
}

// Round 8
// 202.820 us; speedup vs baseline: 1.7168x; 1.2715x over previous
//
#include <hip/hip_runtime.h>
#include <hip/hip_bf16.h>

#define DHID 64
#define SUBSH 9
#define SUBSZ (1 << SUBSH)     // 512 dst nodes per sub-bucket
#define PCAP 16384             // LDS staging cap (ints) in k_place
#define EB 4096                // edges per block in k_bucket
typedef __attribute__((ext_vector_type(8))) short short8;
typedef __attribute__((ext_vector_type(4))) float f32x4;

static __device__ __forceinline__ short tobf(float f) {
  __hip_bfloat16 h = __float2bfloat16(f);
  return *reinterpret_cast<short*>(&h);
}
static __device__ __forceinline__ float frombf(short s) {
  union { unsigned u; float f; } v; v.u = ((unsigned)(unsigned short)s) << 16; return v.f;
}

// ---------- CSR build (no global atomics except per-block bucket bases) ----------
// pass 1: partition edges into 512-node dst sub-buckets; payload packed
// (src<<9)|(d&511) — 26 bits. Appends are block-contiguous runs.
__global__ void k_bucket(const int* __restrict__ src, const int* __restrict__ dst,
                         int* __restrict__ bkt, int* __restrict__ bcnt,
                         int E, int nsb, int cap) {
  __shared__ int lcnt[256];
  __shared__ int lbase[256];
  int tid = threadIdx.x;
  int c0 = blockIdx.x * EB;
  if (c0 >= E) return;
  for (int i = tid; i < nsb; i += 256) lcnt[i] = 0;
  __syncthreads();
  int wloc[16], uloc[16];
  #pragma unroll
  for (int k = 0; k < 16; k++) {
    int i = c0 + tid + k * 256;
    if (i < E) {
      int d = dst[i];
      int w = d >> SUBSH;
      wloc[k] = w;
      uloc[k] = (src[i] << SUBSH) | (d & (SUBSZ - 1));
      atomicAdd(&lcnt[w], 1);
    } else wloc[k] = -1;
  }
  __syncthreads();
  for (int i = tid; i < nsb; i += 256) lbase[i] = atomicAdd(&bcnt[i], lcnt[i]);
  __syncthreads();
  for (int i = tid; i < nsb; i += 256) lcnt[i] = 0;   // reuse as local rank
  __syncthreads();
  #pragma unroll
  for (int k = 0; k < 16; k++) {
    int w = wloc[k];
    if (w >= 0) {
      int r = atomicAdd(&lcnt[w], 1);
      bkt[(size_t)w * cap + lbase[w] + r] = uloc[k];
    }
  }
}

// pass 2: per-sub-bucket LDS histogram -> per-dst counts (coalesced write)
__global__ void k_count(const int* __restrict__ bkt, const int* __restrict__ bcnt,
                        int* __restrict__ roff, int N, int cap) {
  __shared__ int h[SUBSZ];
  int sb = blockIdx.x, tid = threadIdx.x;
  for (int j = tid; j < SUBSZ; j += 256) h[j] = 1;   // self-loop pre-count
  __syncthreads();
  int n = bcnt[sb];
  const int* b = bkt + (size_t)sb * cap;
  for (int i = tid; i < n; i += 256) atomicAdd(&h[b[i] & (SUBSZ - 1)], 1);
  __syncthreads();
  int d0 = sb << SUBSH, d1 = min(N, d0 + SUBSZ);
  for (int j = tid; j < d1 - d0; j += 256) roff[d0 + j] = h[j];
}

__global__ void k_scan_block(int* __restrict__ buf, int n, int* __restrict__ bsum) {
  __shared__ int lds[256];
  int tid = threadIdx.x;
  int base = blockIdx.x * 1024 + tid * 4;
  int a0 = (base + 0) < n ? buf[base + 0] : 0;
  int a1 = (base + 1) < n ? buf[base + 1] : 0;
  int a2 = (base + 2) < n ? buf[base + 2] : 0;
  int a3 = (base + 3) < n ? buf[base + 3] : 0;
  int s = a0 + a1 + a2 + a3;
  lds[tid] = s; __syncthreads();
  for (int off = 1; off < 256; off <<= 1) {
    int t = (tid >= off) ? lds[tid - off] : 0;
    __syncthreads();
    lds[tid] += t;
    __syncthreads();
  }
  int excl = lds[tid] - s;
  if ((base + 0) < n) buf[base + 0] = excl; excl += a0;
  if ((base + 1) < n) buf[base + 1] = excl; excl += a1;
  if ((base + 2) < n) buf[base + 2] = excl; excl += a2;
  if ((base + 3) < n) buf[base + 3] = excl;
  if (tid == 255) bsum[blockIdx.x] = lds[255];
}

__global__ void k_scan_mid(int* __restrict__ bsum, int nb) {
  int lane = threadIdx.x;
  int v0 = (lane < nb) ? bsum[lane] : 0;
  #pragma unroll
  for (int off = 1; off < 64; off <<= 1) { int t = __shfl_up(v0, off, 64); if (lane >= off) v0 += t; }
  int v1 = (64 + lane) < nb ? bsum[64 + lane] : 0;
  #pragma unroll
  for (int off = 1; off < 64; off <<= 1) { int t = __shfl_up(v1, off, 64); if (lane >= off) v1 += t; }
  v1 += __shfl(v0, 63, 64);
  if (lane < nb) bsum[lane] = v0;
  if ((64 + lane) < nb) bsum[64 + lane] = v1;
}

__global__ void k_scan_add(int* __restrict__ buf, int n, const int* __restrict__ bsum, int nb) {
  int i = blockIdx.x * blockDim.x + threadIdx.x;
  if (i < n) { int c = i >> 10; if (c > 0) buf[i] += bsum[c - 1]; }
  if (i == 0) buf[n] = bsum[nb - 1];
}

// pass 3: LDS counting-sort placement (ranks via LDS atomics; self-loop slot 0),
// then one coalesced streaming write of the contiguous csr span.
__global__ void k_place(const int* __restrict__ bkt, const int* __restrict__ bcnt,
                        const int* __restrict__ roff, int* __restrict__ csr,
                        int N, int cap) {
  __shared__ int roff_l[SUBSZ + 1];
  __shared__ int lcnt[SUBSZ];
  __shared__ int stage[PCAP];
  int sb = blockIdx.x, tid = threadIdx.x;
  int d0 = sb << SUBSH;
  int d1 = min(N, d0 + SUBSZ);
  int nn = d1 - d0;
  for (int j = tid; j <= nn; j += 256) roff_l[j] = roff[d0 + j];
  for (int j = tid; j < SUBSZ; j += 256) lcnt[j] = 0;
  __syncthreads();
  int base = roff_l[0];
  int span = roff_l[nn] - base;
  int nE = bcnt[sb];
  const int* b = bkt + (size_t)sb * cap;
  if (span <= PCAP) {
    for (int d = tid; d < nn; d += 256) stage[roff_l[d] - base] = d0 + d;  // self-loop
    for (int i = tid; i < nE; i += 256) {
      int u = b[i];
      int dl = u & (SUBSZ - 1);
      int rk = 1 + atomicAdd(&lcnt[dl], 1);
      stage[roff_l[dl] - base + rk] = u >> SUBSH;
    }
    __syncthreads();
    for (int j = tid; j < span; j += 256) csr[base + j] = stage[j];
  } else {  // correctness fallback (never for random graphs)
    for (int d = tid; d < nn; d += 256) csr[roff_l[d]] = d0 + d;
    for (int i = tid; i < nE; i += 256) {
      int u = b[i];
      int dl = u & (SUBSZ - 1);
      int rk = 1 + atomicAdd(&lcnt[dl], 1);
      csr[roff_l[dl] + rk] = u >> SUBSH;
    }
  }
}

// ---------- prep: x fp32 -> bf16, XOR-swizzled rows (K=128) ----------
__global__ void k_cvt(const float* __restrict__ x, short* __restrict__ xb, int N) {
  int i = blockIdx.x * blockDim.x + threadIdx.x;   // one 8-elem chunk
  int tot = N * 16;
  if (i >= tot) return;
  int row = i >> 4;
  int kc = (i & 15) << 3;
  const float4* xp = (const float4*)(x + (size_t)row * 128 + kc);
  float4 v0 = xp[0], v1 = xp[1];
  short8 o;
  o[0] = tobf(v0.x); o[1] = tobf(v0.y); o[2] = tobf(v0.z); o[3] = tobf(v0.w);
  o[4] = tobf(v1.x); o[5] = tobf(v1.y); o[6] = tobf(v1.z); o[7] = tobf(v1.w);
  int ks = kc ^ ((row & 7) << 3);
  *(short8*)(xb + (size_t)row * 128 + ks) = o;
}

// ---------- prep: W [K][64] -> Wt bf16 [64][K], XOR-swizzled ----------
__global__ void k_prep(const float* __restrict__ W, short* __restrict__ wt, int K) {
  for (int e = threadIdx.x; e < 64 * K; e += blockDim.x) {
    int c = e / K, k = e - c * K;
    wt[c * K + (k ^ ((c & 7) << 3))] = tobf(W[k * 64 + c]);
  }
}

// ---------- MFMA gemm: hb[n][d] = xb[n][:] @ Wt[d][:]^T ; + as/ad dots ----------
template<int K>
__launch_bounds__(256)
__global__ void k_mgemm(const short* __restrict__ xb, const short* __restrict__ wt,
                        const float* __restrict__ a_s, const float* __restrict__ a_d,
                        short* __restrict__ hb, float* __restrict__ asb,
                        float* __restrict__ adb, int N) {
  constexpr int ASZ = 64 * K * 2;          // bytes of A tile (== B tile)
  __shared__ __align__(16) short lds[2 * 64 * K];
  int tid = threadIdx.x;
  int n0 = blockIdx.x * 64;

  const char* ga = (const char*)xb + (size_t)n0 * (K * 2);
  const char* gb = (const char*)wt;
  #pragma unroll
  for (int j = 0; j < (2 * ASZ) / 4096; j++) {
    int d = j * 4096 + tid * 16;
    const char* src = (d < ASZ) ? (ga + d) : (gb + (d - ASZ));
    __builtin_amdgcn_global_load_lds(
        (__attribute__((address_space(1))) const void*)src,
        (__attribute__((address_space(3))) void*)((char*)lds + d), 16, 0, 0);
  }
  __syncthreads();

  int l = tid & 63, w = tid >> 6;
  int c = l & 15, g = l >> 4;
  const short* A = lds;
  const short* B = lds + 64 * K;
  f32x4 acc[4];
  #pragma unroll
  for (int t = 0; t < 4; t++) acc[t] = (f32x4){0.f, 0.f, 0.f, 0.f};

  int arow = 16 * w + c;
  #pragma unroll
  for (int s = 0; s < K / 32; s++) {
    int ke = s * 32 + g * 8;
    short8 af = *(const short8*)(A + arow * K + (ke ^ ((arow & 7) << 3)));
    #pragma unroll
    for (int t = 0; t < 4; t++) {
      int bcol = 16 * t + c;
      short8 bf = *(const short8*)(B + bcol * K + (ke ^ ((bcol & 7) << 3)));
      acc[t] = __builtin_amdgcn_mfma_f32_16x16x32_bf16(af, bf, acc[t], 0, 0, 0);
    }
  }

  float av_s[4], av_d[4];
  #pragma unroll
  for (int t = 0; t < 4; t++) { av_s[t] = a_s[16 * t + c]; av_d[t] = a_d[16 * t + c]; }
  #pragma unroll
  for (int q = 0; q < 4; q++) {
    int row = n0 + 16 * w + g * 4 + q;
    bool ok = row < N;
    float rs = 0.f, rd = 0.f;
    #pragma unroll
    for (int t = 0; t < 4; t++) {
      float v = acc[t][q];
      if (ok) hb[(size_t)row * 64 + 16 * t + c] = tobf(v);
      rs += v * av_s[t]; rd += v * av_d[t];
    }
    #pragma unroll
    for (int off = 1; off < 16; off <<= 1) {
      rs += __shfl_xor(rs, off, 64);
      rd += __shfl_xor(rd, off, 64);
    }
    if (ok && c == 0) { asb[row] = rs; adb[row] = rd; }
  }
}

// ---------- sparse: fused softmax + aggregation, one wave per dst node ----------
__global__ void k_agg(const int* __restrict__ roff, const int* __restrict__ csr,
                      const float* __restrict__ asb, const float* __restrict__ adb,
                      const short* __restrict__ hb, const float* __restrict__ b,
                      float* __restrict__ out, short* __restrict__ outb,
                      int N, int relu) {
  int lane = threadIdx.x & 63;
  int wid = blockIdx.x * (blockDim.x >> 6) + (threadIdx.x >> 6);
  int nw = gridDim.x * (blockDim.x >> 6);
  float bv = b[lane];
  for (int n = wid; n < N; n += nw) {
    int r0 = roff[n], r1 = roff[n + 1];
    float adn = adb[n];
    float acc = 0.f, denl = 0.f;
    for (int base = r0; base < r1; base += 64) {
      int cnt = min(64, r1 - base);
      int s = 0; float e = 0.f;
      if (lane < cnt) {
        s = csr[base + lane];
        float l = asb[s] + adn;
        l = fmaxf(l, 0.2f * l);
        e = __expf(l);
      }
      denl += e;
      for (int j = 0; j < cnt; j += 8) {
        #pragma unroll
        for (int k = 0; k < 8; k++) {
          int   sk = __builtin_amdgcn_readlane(s, j + k);
          float ek = __uint_as_float(__builtin_amdgcn_readlane(__float_as_uint(e), j + k));
          acc += ek * frombf(hb[(size_t)sk * DHID + lane]);
        }
      }
    }
    float den = denl;
    #pragma unroll
    for (int off = 32; off; off >>= 1) den += __shfl_xor(den, off, 64);
    float o = acc / (den + 1e-16f) + bv;
    if (relu) o = fmaxf(o, 0.f);
    out[(size_t)n * DHID + lane] = o;
    if (outb) outb[(size_t)n * DHID + (lane ^ ((n & 7) << 3))] = tobf(o);
  }
}

extern "C" void kernel_launch(void* const* d_in, const int* in_sizes, int n_in,
                              void* d_out, int out_size, void* d_ws, size_t ws_size,
                              hipStream_t stream) {
  const float* x   = (const float*)d_in[0];
  const int*   ei  = (const int*)d_in[1];
  const float* W1  = (const float*)d_in[2];
  const float* as1 = (const float*)d_in[3];
  const float* ad1 = (const float*)d_in[4];
  const float* b1  = (const float*)d_in[5];
  const float* W2  = (const float*)d_in[6];
  const float* as2 = (const float*)d_in[7];
  const float* ad2 = (const float*)d_in[8];
  const float* b2  = (const float*)d_in[9];

  int N = in_sizes[0] / 128;
  int E = in_sizes[1] / 2;
  const int* srcp = ei;
  const int* dstp = ei + E;

  float* emb  = (float*)d_out;
  float* out2 = emb + (size_t)N * DHID;

  char* w = (char*)d_ws;
  auto alloc = [&](size_t bytes) { char* p = w; w += (bytes + 255) & ~(size_t)255; return p; };
  int NR = ((N + 63) / 64) * 64;
  int* roff = (int*)alloc((size_t)(N + 1) * 4);
  int* csr  = (int*)alloc((size_t)(E + N) * 4);
  int* bsum = (int*)alloc(2048);
  short* xb = (short*)alloc((size_t)NR * 128 * 2);
  short* hb = (short*)alloc((size_t)NR * 64 * 2);
  float* asb = (float*)alloc((size_t)N * 4);
  float* adb = (float*)alloc((size_t)N * 4);
  short* wt1 = (short*)alloc(64 * 128 * 2);
  short* wt2 = (short*)alloc(64 * 64 * 2);
  short* eb = xb;                 // overlay: xb dead after mgemm1
  int* bkt  = (int*)xb;           // overlay: buckets dead before k_cvt writes xb
  int* bcnt = (int*)hb;           // overlay: hb dead until mgemm1

  int nsb = (N + SUBSZ - 1) >> SUBSH;          // 196 sub-buckets
  int cap = E / nsb + 4096;                    // per-sub-bucket capacity (ints)

  int nb = (N + 1023) / 1024;
  int NBLK = (N + 63) / 64;

  hipMemsetAsync(bcnt, 0, (size_t)nsb * 4, stream);
  k_bucket<<<(E + EB - 1) / EB, 256, 0, stream>>>(srcp, dstp, bkt, bcnt, E, nsb, cap);
  k_count<<<nsb, 256, 0, stream>>>(bkt, bcnt, roff, N, cap);
  k_scan_block<<<nb, 256, 0, stream>>>(roff, N, bsum);
  k_scan_mid<<<1, 64, 0, stream>>>(bsum, nb);
  k_scan_add<<<(N + 255) / 256, 256, 0, stream>>>(roff, N, bsum, nb);
  k_place<<<nsb, 256, 0, stream>>>(bkt, bcnt, roff, csr, N, cap);

  // buckets now dead -> safe to overwrite xb/hb
  k_prep<<<1, 256, 0, stream>>>(W1, wt1, 128);
  k_prep<<<1, 256, 0, stream>>>(W2, wt2, 64);
  k_cvt<<<(N * 16 + 255) / 256, 256, 0, stream>>>(x, xb, N);

  k_mgemm<128><<<NBLK, 256, 0, stream>>>(xb, wt1, as1, ad1, hb, asb, adb, N);
  k_agg<<<2048, 256, 0, stream>>>(roff, csr, asb, adb, hb, b1, emb, eb, N, 1);
  k_mgemm<64><<<NBLK, 256, 0, stream>>>(eb, wt2, as2, ad2, hb, asb, adb, N);
  k_agg<<<2048, 256, 0, stream>>>(roff, csr, asb, adb, hb, b2, out2, (short*)nullptr, N, 0);
}

// Round 9
// 199.263 us; speedup vs baseline: 1.7475x; 1.0179x over previous
//
#include <hip/hip_runtime.h>
#include <hip/hip_bf16.h>

#define DHID 64
#define SUBSH 9
#define SUBSZ (1 << SUBSH)     // 512 dst nodes per sub-bucket
#define PCAP 16384             // LDS staging cap (ints) in k_place
#define EB 4096                // edges per block in k_bucket
typedef __attribute__((ext_vector_type(8))) short short8;
typedef __attribute__((ext_vector_type(4))) float f32x4;
typedef __attribute__((ext_vector_type(4))) int int4v;

static __device__ __forceinline__ short tobf(float f) {
  __hip_bfloat16 h = __float2bfloat16(f);
  return *reinterpret_cast<short*>(&h);
}
static __device__ __forceinline__ float frombf(short s) {
  union { unsigned u; float f; } v; v.u = ((unsigned)(unsigned short)s) << 16; return v.f;
}

// ---------- CSR build ----------
// pass 1: partition edges into 512-node dst sub-buckets; payload packed
// (src<<9)|(d&511) — 26 bits. Appends are block-contiguous runs.
__global__ void k_bucket(const int* __restrict__ src, const int* __restrict__ dst,
                         int* __restrict__ bkt, int* __restrict__ bcnt,
                         int E, int nsb, int cap) {
  __shared__ int lcnt[256];
  __shared__ int lbase[256];
  int tid = threadIdx.x;
  int c0 = blockIdx.x * EB;
  if (c0 >= E) return;
  for (int i = tid; i < nsb; i += 256) lcnt[i] = 0;
  __syncthreads();
  int wloc[16], uloc[16];
  #pragma unroll
  for (int k = 0; k < 16; k++) {
    int i = c0 + tid + k * 256;
    if (i < E) {
      int d = dst[i];
      int w = d >> SUBSH;
      wloc[k] = w;
      uloc[k] = (src[i] << SUBSH) | (d & (SUBSZ - 1));
      atomicAdd(&lcnt[w], 1);
    } else wloc[k] = -1;
  }
  __syncthreads();
  for (int i = tid; i < nsb; i += 256) lbase[i] = atomicAdd(&bcnt[i], lcnt[i]);
  __syncthreads();
  for (int i = tid; i < nsb; i += 256) lcnt[i] = 0;   // reuse as local rank
  __syncthreads();
  #pragma unroll
  for (int k = 0; k < 16; k++) {
    int w = wloc[k];
    if (w >= 0) {
      int r = atomicAdd(&lcnt[w], 1);
      bkt[(size_t)w * cap + lbase[w] + r] = uloc[k];
    }
  }
}

// pass 2: per-sub-bucket LDS histogram -> per-dst counts (coalesced write)
__global__ void k_count(const int* __restrict__ bkt, const int* __restrict__ bcnt,
                        int* __restrict__ roff, int N, int cap) {
  __shared__ int h[SUBSZ];
  int sb = blockIdx.x, tid = threadIdx.x;
  for (int j = tid; j < SUBSZ; j += 256) h[j] = 1;   // self-loop pre-count
  __syncthreads();
  int n = bcnt[sb];
  const int* b = bkt + (size_t)sb * cap;
  for (int i = tid; i < n; i += 256) atomicAdd(&h[b[i] & (SUBSZ - 1)], 1);
  __syncthreads();
  int d0 = sb << SUBSH, d1 = min(N, d0 + SUBSZ);
  for (int j = tid; j < d1 - d0; j += 256) roff[d0 + j] = h[j];
}

__global__ void k_scan_block(int* __restrict__ buf, int n, int* __restrict__ bsum) {
  __shared__ int lds[256];
  int tid = threadIdx.x;
  int base = blockIdx.x * 1024 + tid * 4;
  int a0 = (base + 0) < n ? buf[base + 0] : 0;
  int a1 = (base + 1) < n ? buf[base + 1] : 0;
  int a2 = (base + 2) < n ? buf[base + 2] : 0;
  int a3 = (base + 3) < n ? buf[base + 3] : 0;
  int s = a0 + a1 + a2 + a3;
  lds[tid] = s; __syncthreads();
  for (int off = 1; off < 256; off <<= 1) {
    int t = (tid >= off) ? lds[tid - off] : 0;
    __syncthreads();
    lds[tid] += t;
    __syncthreads();
  }
  int excl = lds[tid] - s;
  if ((base + 0) < n) buf[base + 0] = excl; excl += a0;
  if ((base + 1) < n) buf[base + 1] = excl; excl += a1;
  if ((base + 2) < n) buf[base + 2] = excl; excl += a2;
  if ((base + 3) < n) buf[base + 3] = excl;
  if (tid == 255) bsum[blockIdx.x] = lds[255];
}

__global__ void k_scan_mid(int* __restrict__ bsum, int nb) {
  int lane = threadIdx.x;
  int v0 = (lane < nb) ? bsum[lane] : 0;
  #pragma unroll
  for (int off = 1; off < 64; off <<= 1) { int t = __shfl_up(v0, off, 64); if (lane >= off) v0 += t; }
  int v1 = (64 + lane) < nb ? bsum[64 + lane] : 0;
  #pragma unroll
  for (int off = 1; off < 64; off <<= 1) { int t = __shfl_up(v1, off, 64); if (lane >= off) v1 += t; }
  v1 += __shfl(v0, 63, 64);
  if (lane < nb) bsum[lane] = v0;
  if ((64 + lane) < nb) bsum[64 + lane] = v1;
}

__global__ void k_scan_add(int* __restrict__ buf, int n, const int* __restrict__ bsum, int nb) {
  int i = blockIdx.x * blockDim.x + threadIdx.x;
  if (i < n) { int c = i >> 10; if (c > 0) buf[i] += bsum[c - 1]; }
  if (i == 0) buf[n] = bsum[nb - 1];
}

// pass 3: LDS counting-sort placement; csr stores BYTE offsets (src*128) so the
// aggregation kernel can use 32-bit buffer addressing with zero 64-bit math.
__global__ void k_place(const int* __restrict__ bkt, const int* __restrict__ bcnt,
                        const int* __restrict__ roff, int* __restrict__ csr,
                        int N, int cap) {
  __shared__ int roff_l[SUBSZ + 1];
  __shared__ int lcnt[SUBSZ];
  __shared__ int stage[PCAP];
  int sb = blockIdx.x, tid = threadIdx.x;
  int d0 = sb << SUBSH;
  int d1 = min(N, d0 + SUBSZ);
  int nn = d1 - d0;
  for (int j = tid; j <= nn; j += 256) roff_l[j] = roff[d0 + j];
  for (int j = tid; j < SUBSZ; j += 256) lcnt[j] = 0;
  __syncthreads();
  int base = roff_l[0];
  int span = roff_l[nn] - base;
  int nE = bcnt[sb];
  const int* b = bkt + (size_t)sb * cap;
  if (span <= PCAP) {
    for (int d = tid; d < nn; d += 256) stage[roff_l[d] - base] = (d0 + d) << 7;  // self-loop
    for (int i = tid; i < nE; i += 256) {
      int u = b[i];
      int dl = u & (SUBSZ - 1);
      int rk = 1 + atomicAdd(&lcnt[dl], 1);
      stage[roff_l[dl] - base + rk] = (u >> SUBSH) << 7;
    }
    __syncthreads();
    for (int j = tid; j < span; j += 256) csr[base + j] = stage[j];
  } else {  // correctness fallback (never for random graphs)
    for (int d = tid; d < nn; d += 256) csr[roff_l[d]] = (d0 + d) << 7;
    for (int i = tid; i < nE; i += 256) {
      int u = b[i];
      int dl = u & (SUBSZ - 1);
      int rk = 1 + atomicAdd(&lcnt[dl], 1);
      csr[roff_l[dl] + rk] = (u >> SUBSH) << 7;
    }
  }
}

// ---------- prep: x fp32 -> bf16, XOR-swizzled rows (K=128) ----------
__global__ void k_cvt(const float* __restrict__ x, short* __restrict__ xb, int N) {
  int i = blockIdx.x * blockDim.x + threadIdx.x;   // one 8-elem chunk
  int tot = N * 16;
  if (i >= tot) return;
  int row = i >> 4;
  int kc = (i & 15) << 3;
  const float4* xp = (const float4*)(x + (size_t)row * 128 + kc);
  float4 v0 = xp[0], v1 = xp[1];
  short8 o;
  o[0] = tobf(v0.x); o[1] = tobf(v0.y); o[2] = tobf(v0.z); o[3] = tobf(v0.w);
  o[4] = tobf(v1.x); o[5] = tobf(v1.y); o[6] = tobf(v1.z); o[7] = tobf(v1.w);
  int ks = kc ^ ((row & 7) << 3);
  *(short8*)(xb + (size_t)row * 128 + ks) = o;
}

// ---------- prep: W [K][64] -> Wt bf16 [64][K], XOR-swizzled ----------
__global__ void k_prep(const float* __restrict__ W, short* __restrict__ wt, int K) {
  for (int e = threadIdx.x; e < 64 * K; e += blockDim.x) {
    int c = e / K, k = e - c * K;
    wt[c * K + (k ^ ((c & 7) << 3))] = tobf(W[k * 64 + c]);
  }
}

// ---------- MFMA gemm: hb[n][d] = xb[n][:] @ Wt[d][:]^T ; + as/ad dots ----------
template<int K>
__launch_bounds__(256)
__global__ void k_mgemm(const short* __restrict__ xb, const short* __restrict__ wt,
                        const float* __restrict__ a_s, const float* __restrict__ a_d,
                        short* __restrict__ hb, float* __restrict__ asb,
                        float* __restrict__ adb, int N) {
  constexpr int ASZ = 64 * K * 2;          // bytes of A tile (== B tile)
  __shared__ __align__(16) short lds[2 * 64 * K];
  int tid = threadIdx.x;
  int n0 = blockIdx.x * 64;

  const char* ga = (const char*)xb + (size_t)n0 * (K * 2);
  const char* gb = (const char*)wt;
  #pragma unroll
  for (int j = 0; j < (2 * ASZ) / 4096; j++) {
    int d = j * 4096 + tid * 16;
    const char* src = (d < ASZ) ? (ga + d) : (gb + (d - ASZ));
    __builtin_amdgcn_global_load_lds(
        (__attribute__((address_space(1))) const void*)src,
        (__attribute__((address_space(3))) void*)((char*)lds + d), 16, 0, 0);
  }
  __syncthreads();

  int l = tid & 63, w = tid >> 6;
  int c = l & 15, g = l >> 4;
  const short* A = lds;
  const short* B = lds + 64 * K;
  f32x4 acc[4];
  #pragma unroll
  for (int t = 0; t < 4; t++) acc[t] = (f32x4){0.f, 0.f, 0.f, 0.f};

  int arow = 16 * w + c;
  #pragma unroll
  for (int s = 0; s < K / 32; s++) {
    int ke = s * 32 + g * 8;
    short8 af = *(const short8*)(A + arow * K + (ke ^ ((arow & 7) << 3)));
    #pragma unroll
    for (int t = 0; t < 4; t++) {
      int bcol = 16 * t + c;
      short8 bf = *(const short8*)(B + bcol * K + (ke ^ ((bcol & 7) << 3)));
      acc[t] = __builtin_amdgcn_mfma_f32_16x16x32_bf16(af, bf, acc[t], 0, 0, 0);
    }
  }

  float av_s[4], av_d[4];
  #pragma unroll
  for (int t = 0; t < 4; t++) { av_s[t] = a_s[16 * t + c]; av_d[t] = a_d[16 * t + c]; }
  #pragma unroll
  for (int q = 0; q < 4; q++) {
    int row = n0 + 16 * w + g * 4 + q;
    bool ok = row < N;
    float rs = 0.f, rd = 0.f;
    #pragma unroll
    for (int t = 0; t < 4; t++) {
      float v = acc[t][q];
      if (ok) hb[(size_t)row * 64 + 16 * t + c] = tobf(v);
      rs += v * av_s[t]; rd += v * av_d[t];
    }
    #pragma unroll
    for (int off = 1; off < 16; off <<= 1) {
      rs += __shfl_xor(rs, off, 64);
      rd += __shfl_xor(rd, off, 64);
    }
    if (ok && c == 0) { asb[row] = rs; adb[row] = rd; }
  }
}

// ---------- sparse: fused softmax + aggregation, one wave per dst node ----------
// csr holds byte offsets (src*128). Phase 2 uses SRSRC buffer loads with
// d16_hi destinations: per edge = readlane + readlane + v_add + fmac.
__global__ void k_agg(const int* __restrict__ roff, const int* __restrict__ csr,
                      const float* __restrict__ asb, const float* __restrict__ adb,
                      const short* __restrict__ hb, const float* __restrict__ b,
                      float* __restrict__ out, short* __restrict__ outb,
                      int N, int relu, int hb_bytes) {
  union { const short* p; unsigned u[2]; } up; up.p = hb;
  int4v rsrc;
  rsrc[0] = (int)up.u[0];
  rsrc[1] = (int)(up.u[1] & 0xffffu);   // base hi16, stride=0
  rsrc[2] = hb_bytes;                    // num_records (bytes)
  rsrc[3] = 0x00020000;                  // raw dword access
  int lane = threadIdx.x & 63;
  unsigned lane2 = (unsigned)lane * 2u;
  int wid = blockIdx.x * (blockDim.x >> 6) + (threadIdx.x >> 6);
  int nw = gridDim.x * (blockDim.x >> 6);
  float bv = b[lane];
  // d16_hi destinations: low halves zeroed ONCE; loads only write the hi half,
  // so each register is directly the f32 value (bf16<<16).
  float h0 = 0.f, h1 = 0.f, h2 = 0.f, h3 = 0.f, h4 = 0.f, h5 = 0.f, h6 = 0.f, h7 = 0.f;
  for (int n = wid; n < N; n += nw) {
    int r0 = roff[n], r1 = roff[n + 1];
    float adn = adb[n];
    float acc = 0.f, denl = 0.f;
    for (int base = r0; base < r1; base += 64) {
      int cnt = min(64, r1 - base);
      int s128 = 0; float e = 0.f;
      if (lane < cnt) {
        s128 = csr[base + lane];          // byte offset src*128
        float l = asb[s128 >> 7] + adn;
        l = fmaxf(l, 0.2f * l);
        e = __expf(l);
      }
      denl += e;
      for (int j = 0; j < cnt; j += 8) {
        unsigned o0, o1, o2, o3, o4, o5, o6, o7;
        unsigned so, se, sj;
        asm volatile(
          "s_mov_b32 %[sj], %[j]\n\t"
          "v_readlane_b32 %[so], %[vs], %[sj]\n\t"
          "v_add_u32 %[o0], %[so], %[vl]\n\t"
          "buffer_load_short_d16_hi %[h0], %[o0], %[rs], 0 offen\n\t"
          "s_add_u32 %[sj], %[sj], 1\n\t"
          "v_readlane_b32 %[so], %[vs], %[sj]\n\t"
          "v_add_u32 %[o1], %[so], %[vl]\n\t"
          "buffer_load_short_d16_hi %[h1], %[o1], %[rs], 0 offen\n\t"
          "s_add_u32 %[sj], %[sj], 1\n\t"
          "v_readlane_b32 %[so], %[vs], %[sj]\n\t"
          "v_add_u32 %[o2], %[so], %[vl]\n\t"
          "buffer_load_short_d16_hi %[h2], %[o2], %[rs], 0 offen\n\t"
          "s_add_u32 %[sj], %[sj], 1\n\t"
          "v_readlane_b32 %[so], %[vs], %[sj]\n\t"
          "v_add_u32 %[o3], %[so], %[vl]\n\t"
          "buffer_load_short_d16_hi %[h3], %[o3], %[rs], 0 offen\n\t"
          "s_add_u32 %[sj], %[sj], 1\n\t"
          "v_readlane_b32 %[so], %[vs], %[sj]\n\t"
          "v_add_u32 %[o4], %[so], %[vl]\n\t"
          "buffer_load_short_d16_hi %[h4], %[o4], %[rs], 0 offen\n\t"
          "s_add_u32 %[sj], %[sj], 1\n\t"
          "v_readlane_b32 %[so], %[vs], %[sj]\n\t"
          "v_add_u32 %[o5], %[so], %[vl]\n\t"
          "buffer_load_short_d16_hi %[h5], %[o5], %[rs], 0 offen\n\t"
          "s_add_u32 %[sj], %[sj], 1\n\t"
          "v_readlane_b32 %[so], %[vs], %[sj]\n\t"
          "v_add_u32 %[o6], %[so], %[vl]\n\t"
          "buffer_load_short_d16_hi %[h6], %[o6], %[rs], 0 offen\n\t"
          "s_add_u32 %[sj], %[sj], 1\n\t"
          "v_readlane_b32 %[so], %[vs], %[sj]\n\t"
          "v_add_u32 %[o7], %[so], %[vl]\n\t"
          "buffer_load_short_d16_hi %[h7], %[o7], %[rs], 0 offen\n\t"
          "s_mov_b32 %[sj], %[j]\n\t"
          "s_waitcnt vmcnt(0)\n\t"
          "v_readlane_b32 %[se], %[ve], %[sj]\n\t"
          "v_fmac_f32 %[acc], %[se], %[h0]\n\t"
          "s_add_u32 %[sj], %[sj], 1\n\t"
          "v_readlane_b32 %[se], %[ve], %[sj]\n\t"
          "v_fmac_f32 %[acc], %[se], %[h1]\n\t"
          "s_add_u32 %[sj], %[sj], 1\n\t"
          "v_readlane_b32 %[se], %[ve], %[sj]\n\t"
          "v_fmac_f32 %[acc], %[se], %[h2]\n\t"
          "s_add_u32 %[sj], %[sj], 1\n\t"
          "v_readlane_b32 %[se], %[ve], %[sj]\n\t"
          "v_fmac_f32 %[acc], %[se], %[h3]\n\t"
          "s_add_u32 %[sj], %[sj], 1\n\t"
          "v_readlane_b32 %[se], %[ve], %[sj]\n\t"
          "v_fmac_f32 %[acc], %[se], %[h4]\n\t"
          "s_add_u32 %[sj], %[sj], 1\n\t"
          "v_readlane_b32 %[se], %[ve], %[sj]\n\t"
          "v_fmac_f32 %[acc], %[se], %[h5]\n\t"
          "s_add_u32 %[sj], %[sj], 1\n\t"
          "v_readlane_b32 %[se], %[ve], %[sj]\n\t"
          "v_fmac_f32 %[acc], %[se], %[h6]\n\t"
          "s_add_u32 %[sj], %[sj], 1\n\t"
          "v_readlane_b32 %[se], %[ve], %[sj]\n\t"
          "v_fmac_f32 %[acc], %[se], %[h7]\n\t"
          : [acc]"+v"(acc),
            [h0]"+v"(h0), [h1]"+v"(h1), [h2]"+v"(h2), [h3]"+v"(h3),
            [h4]"+v"(h4), [h5]"+v"(h5), [h6]"+v"(h6), [h7]"+v"(h7),
            [o0]"=&v"(o0), [o1]"=&v"(o1), [o2]"=&v"(o2), [o3]"=&v"(o3),
            [o4]"=&v"(o4), [o5]"=&v"(o5), [o6]"=&v"(o6), [o7]"=&v"(o7),
            [so]"=&s"(so), [se]"=&s"(se), [sj]"=&s"(sj)
          : [vs]"v"(s128), [ve]"v"(e), [j]"s"(j), [vl]"v"(lane2), [rs]"s"(rsrc));
      }
    }
    float den = denl;
    #pragma unroll
    for (int off = 32; off; off >>= 1) den += __shfl_xor(den, off, 64);
    float o = acc / (den + 1e-16f) + bv;
    if (relu) o = fmaxf(o, 0.f);
    out[(size_t)n * DHID + lane] = o;
    if (outb) outb[(size_t)n * DHID + (lane ^ ((n & 7) << 3))] = tobf(o);
  }
}

extern "C" void kernel_launch(void* const* d_in, const int* in_sizes, int n_in,
                              void* d_out, int out_size, void* d_ws, size_t ws_size,
                              hipStream_t stream) {
  const float* x   = (const float*)d_in[0];
  const int*   ei  = (const int*)d_in[1];
  const float* W1  = (const float*)d_in[2];
  const float* as1 = (const float*)d_in[3];
  const float* ad1 = (const float*)d_in[4];
  const float* b1  = (const float*)d_in[5];
  const float* W2  = (const float*)d_in[6];
  const float* as2 = (const float*)d_in[7];
  const float* ad2 = (const float*)d_in[8];
  const float* b2  = (const float*)d_in[9];

  int N = in_sizes[0] / 128;
  int E = in_sizes[1] / 2;
  const int* srcp = ei;
  const int* dstp = ei + E;

  float* emb  = (float*)d_out;
  float* out2 = emb + (size_t)N * DHID;

  char* w = (char*)d_ws;
  auto alloc = [&](size_t bytes) { char* p = w; w += (bytes + 255) & ~(size_t)255; return p; };
  int NR = ((N + 63) / 64) * 64;
  int* roff = (int*)alloc((size_t)(N + 1) * 4);
  int* csr  = (int*)alloc((size_t)(E + N) * 4);
  int* bsum = (int*)alloc(2048);
  short* xb = (short*)alloc((size_t)NR * 128 * 2);
  short* hb = (short*)alloc((size_t)NR * 64 * 2);
  float* asb = (float*)alloc((size_t)N * 4);
  float* adb = (float*)alloc((size_t)N * 4);
  short* wt1 = (short*)alloc(64 * 128 * 2);
  short* wt2 = (short*)alloc(64 * 64 * 2);
  short* eb = xb;                 // overlay: xb dead after mgemm1
  int* bkt  = (int*)xb;           // overlay: buckets dead before k_cvt writes xb
  int* bcnt = (int*)hb;           // overlay: hb dead until mgemm1

  int nsb = (N + SUBSZ - 1) >> SUBSH;          // 196 sub-buckets
  int cap = E / nsb + 4096;                    // per-sub-bucket capacity (ints)
  int hb_bytes = NR * 128;

  int nb = (N + 1023) / 1024;
  int NBLK = (N + 63) / 64;

  hipMemsetAsync(bcnt, 0, (size_t)nsb * 4, stream);
  k_bucket<<<(E + EB - 1) / EB, 256, 0, stream>>>(srcp, dstp, bkt, bcnt, E, nsb, cap);
  k_count<<<nsb, 256, 0, stream>>>(bkt, bcnt, roff, N, cap);
  k_scan_block<<<nb, 256, 0, stream>>>(roff, N, bsum);
  k_scan_mid<<<1, 64, 0, stream>>>(bsum, nb);
  k_scan_add<<<(N + 255) / 256, 256, 0, stream>>>(roff, N, bsum, nb);
  k_place<<<nsb, 256, 0, stream>>>(bkt, bcnt, roff, csr, N, cap);

  // buckets now dead -> safe to overwrite xb/hb
  k_prep<<<1, 256, 0, stream>>>(W1, wt1, 128);
  k_prep<<<1, 256, 0, stream>>>(W2, wt2, 64);
  k_cvt<<<(N * 16 + 255) / 256, 256, 0, stream>>>(x, xb, N);

  k_mgemm<128><<<NBLK, 256, 0, stream>>>(xb, wt1, as1, ad1, hb, asb, adb, N);
  k_agg<<<2048, 256, 0, stream>>>(roff, csr, asb, adb, hb, b1, emb, eb, N, 1, hb_bytes);
  k_mgemm<64><<<NBLK, 256, 0, stream>>>(eb, wt2, as2, ad2, hb, asb, adb, N);
  k_agg<<<2048, 256, 0, stream>>>(roff, csr, asb, adb, hb, b2, out2, (short*)nullptr, N, 0, hb_bytes);
}

// Round 10
// 190.888 us; speedup vs baseline: 1.8241x; 1.0439x over previous
//
#include <hip/hip_runtime.h>
#include <hip/hip_bf16.h>

#define DHID 64
#define SUBSH 9
#define SUBSZ (1 << SUBSH)     // 512 dst nodes per sub-bucket
#define PCAP 16384             // LDS staging cap (ints) in k_place
#define EB 4096                // edges per block in k_bucket
typedef __attribute__((ext_vector_type(8))) short short8;
typedef __attribute__((ext_vector_type(4))) float f32x4;
typedef __attribute__((ext_vector_type(4))) int int4v;

static __device__ __forceinline__ short tobf(float f) {
  __hip_bfloat16 h = __float2bfloat16(f);
  return *reinterpret_cast<short*>(&h);
}

// ---------- CSR build ----------
__global__ void k_bucket(const int* __restrict__ src, const int* __restrict__ dst,
                         int* __restrict__ bkt, int* __restrict__ bcnt,
                         int E, int nsb, int cap) {
  __shared__ int lcnt[256];
  __shared__ int lbase[256];
  int tid = threadIdx.x;
  int c0 = blockIdx.x * EB;
  if (c0 >= E) return;
  for (int i = tid; i < nsb; i += 256) lcnt[i] = 0;
  __syncthreads();
  int wloc[16], uloc[16];
  #pragma unroll
  for (int k = 0; k < 16; k++) {
    int i = c0 + tid + k * 256;
    if (i < E) {
      int d = dst[i];
      int w = d >> SUBSH;
      wloc[k] = w;
      uloc[k] = (src[i] << SUBSH) | (d & (SUBSZ - 1));
      atomicAdd(&lcnt[w], 1);
    } else wloc[k] = -1;
  }
  __syncthreads();
  for (int i = tid; i < nsb; i += 256) lbase[i] = atomicAdd(&bcnt[i], lcnt[i]);
  __syncthreads();
  for (int i = tid; i < nsb; i += 256) lcnt[i] = 0;   // reuse as local rank
  __syncthreads();
  #pragma unroll
  for (int k = 0; k < 16; k++) {
    int w = wloc[k];
    if (w >= 0) {
      int r = atomicAdd(&lcnt[w], 1);
      bkt[(size_t)w * cap + lbase[w] + r] = uloc[k];
    }
  }
}

__global__ void k_count(const int* __restrict__ bkt, const int* __restrict__ bcnt,
                        int* __restrict__ roff, int N, int cap) {
  __shared__ int h[SUBSZ];
  int sb = blockIdx.x, tid = threadIdx.x;
  for (int j = tid; j < SUBSZ; j += 256) h[j] = 1;   // self-loop pre-count
  __syncthreads();
  int n = bcnt[sb];
  const int* b = bkt + (size_t)sb * cap;
  for (int i = tid; i < n; i += 256) atomicAdd(&h[b[i] & (SUBSZ - 1)], 1);
  __syncthreads();
  int d0 = sb << SUBSH, d1 = min(N, d0 + SUBSZ);
  for (int j = tid; j < d1 - d0; j += 256) roff[d0 + j] = h[j];
}

__global__ void k_scan_block(int* __restrict__ buf, int n, int* __restrict__ bsum) {
  __shared__ int lds[256];
  int tid = threadIdx.x;
  int base = blockIdx.x * 1024 + tid * 4;
  int a0 = (base + 0) < n ? buf[base + 0] : 0;
  int a1 = (base + 1) < n ? buf[base + 1] : 0;
  int a2 = (base + 2) < n ? buf[base + 2] : 0;
  int a3 = (base + 3) < n ? buf[base + 3] : 0;
  int s = a0 + a1 + a2 + a3;
  lds[tid] = s; __syncthreads();
  for (int off = 1; off < 256; off <<= 1) {
    int t = (tid >= off) ? lds[tid - off] : 0;
    __syncthreads();
    lds[tid] += t;
    __syncthreads();
  }
  int excl = lds[tid] - s;
  if ((base + 0) < n) buf[base + 0] = excl; excl += a0;
  if ((base + 1) < n) buf[base + 1] = excl; excl += a1;
  if ((base + 2) < n) buf[base + 2] = excl; excl += a2;
  if ((base + 3) < n) buf[base + 3] = excl;
  if (tid == 255) bsum[blockIdx.x] = lds[255];
}

__global__ void k_scan_mid(int* __restrict__ bsum, int nb) {
  int lane = threadIdx.x;
  int v0 = (lane < nb) ? bsum[lane] : 0;
  #pragma unroll
  for (int off = 1; off < 64; off <<= 1) { int t = __shfl_up(v0, off, 64); if (lane >= off) v0 += t; }
  int v1 = (64 + lane) < nb ? bsum[64 + lane] : 0;
  #pragma unroll
  for (int off = 1; off < 64; off <<= 1) { int t = __shfl_up(v1, off, 64); if (lane >= off) v1 += t; }
  v1 += __shfl(v0, 63, 64);
  if (lane < nb) bsum[lane] = v0;
  if ((64 + lane) < nb) bsum[64 + lane] = v1;
}

__global__ void k_scan_add(int* __restrict__ buf, int n, const int* __restrict__ bsum, int nb) {
  int i = blockIdx.x * blockDim.x + threadIdx.x;
  if (i < n) { int c = i >> 10; if (c > 0) buf[i] += bsum[c - 1]; }
  if (i == 0) buf[n] = bsum[nb - 1];
}

// pass 3: LDS counting-sort placement; csr stores BYTE offsets (src*128)
__global__ void k_place(const int* __restrict__ bkt, const int* __restrict__ bcnt,
                        const int* __restrict__ roff, int* __restrict__ csr,
                        int N, int cap) {
  __shared__ int roff_l[SUBSZ + 1];
  __shared__ int lcnt[SUBSZ];
  __shared__ int stage[PCAP];
  int sb = blockIdx.x, tid = threadIdx.x;
  int d0 = sb << SUBSH;
  int d1 = min(N, d0 + SUBSZ);
  int nn = d1 - d0;
  for (int j = tid; j <= nn; j += 256) roff_l[j] = roff[d0 + j];
  for (int j = tid; j < SUBSZ; j += 256) lcnt[j] = 0;
  __syncthreads();
  int base = roff_l[0];
  int span = roff_l[nn] - base;
  int nE = bcnt[sb];
  const int* b = bkt + (size_t)sb * cap;
  if (span <= PCAP) {
    for (int d = tid; d < nn; d += 256) stage[roff_l[d] - base] = (d0 + d) << 7;  // self-loop
    for (int i = tid; i < nE; i += 256) {
      int u = b[i];
      int dl = u & (SUBSZ - 1);
      int rk = 1 + atomicAdd(&lcnt[dl], 1);
      stage[roff_l[dl] - base + rk] = (u >> SUBSH) << 7;
    }
    __syncthreads();
    for (int j = tid; j < span; j += 256) csr[base + j] = stage[j];
  } else {  // correctness fallback (never for random graphs)
    for (int d = tid; d < nn; d += 256) csr[roff_l[d]] = (d0 + d) << 7;
    for (int i = tid; i < nE; i += 256) {
      int u = b[i];
      int dl = u & (SUBSZ - 1);
      int rk = 1 + atomicAdd(&lcnt[dl], 1);
      csr[roff_l[dl] + rk] = (u >> SUBSH) << 7;
    }
  }
}

// ---------- prep: W [K][64] -> Wt bf16 [64][K], XOR-swizzled (grid-parallel) ----------
__global__ void k_prep(const float* __restrict__ W, short* __restrict__ wt, int K) {
  int stride = gridDim.x * blockDim.x;
  for (int e = blockIdx.x * blockDim.x + threadIdx.x; e < 64 * K; e += stride) {
    int k = e >> 6, c = e & 63;                        // coalesced read W[k][c]
    wt[c * K + (k ^ ((c & 7) << 3))] = tobf(W[e]);
  }
}

// ---------- MFMA gemm ----------
// AF32=1: A loaded per-lane from fp32 x, converted in-reg (no LDS, no cvt pass).
// AF32=0: A (bf16, pre-swizzled) staged to LDS via global_load_lds.
template<int K, int AF32>
__launch_bounds__(256)
__global__ void k_mgemm(const float* __restrict__ xf, const short* __restrict__ xb,
                        const short* __restrict__ wt,
                        const float* __restrict__ a_s, const float* __restrict__ a_d,
                        short* __restrict__ hb, float* __restrict__ asb,
                        float* __restrict__ adb, int N) {
  constexpr int ASZ = 64 * K * 2;          // bytes of one bf16 tile
  __shared__ __align__(16) short lds[(AF32 ? 1 : 2) * 64 * K];
  int tid = threadIdx.x;
  int n0 = blockIdx.x * 64;

  if (AF32) {
    const char* gb = (const char*)wt;
    #pragma unroll
    for (int j = 0; j < ASZ / 4096; j++) {
      int d = j * 4096 + tid * 16;
      __builtin_amdgcn_global_load_lds(
          (__attribute__((address_space(1))) const void*)(gb + d),
          (__attribute__((address_space(3))) void*)((char*)lds + d), 16, 0, 0);
    }
  } else {
    const char* ga = (const char*)xb + (size_t)n0 * (K * 2);
    const char* gb = (const char*)wt;
    #pragma unroll
    for (int j = 0; j < (2 * ASZ) / 4096; j++) {
      int d = j * 4096 + tid * 16;
      const char* src = (d < ASZ) ? (ga + d) : (gb + (d - ASZ));
      __builtin_amdgcn_global_load_lds(
          (__attribute__((address_space(1))) const void*)src,
          (__attribute__((address_space(3))) void*)((char*)lds + d), 16, 0, 0);
    }
  }
  __syncthreads();

  int l = tid & 63, w = tid >> 6;
  int c = l & 15, g = l >> 4;
  const short* A = lds;
  const short* B = AF32 ? lds : lds + 64 * K;
  f32x4 acc[4];
  #pragma unroll
  for (int t = 0; t < 4; t++) acc[t] = (f32x4){0.f, 0.f, 0.f, 0.f};

  int arow = 16 * w + c;
  short8 afr[K / 32];
  if (AF32) {
    int row = n0 + arow;
    const float* xr = xf + (size_t)row * 128;
    bool okr = row < N;
    #pragma unroll
    for (int s = 0; s < K / 32; s++) {
      int ke = s * 32 + g * 8;
      float4 u0 = make_float4(0.f, 0.f, 0.f, 0.f), u1 = u0;
      if (okr) { u0 = *(const float4*)(xr + ke); u1 = *(const float4*)(xr + ke + 4); }
      short8 af;
      af[0] = tobf(u0.x); af[1] = tobf(u0.y); af[2] = tobf(u0.z); af[3] = tobf(u0.w);
      af[4] = tobf(u1.x); af[5] = tobf(u1.y); af[6] = tobf(u1.z); af[7] = tobf(u1.w);
      afr[s] = af;
    }
  }

  #pragma unroll
  for (int s = 0; s < K / 32; s++) {
    int ke = s * 32 + g * 8;
    short8 af;
    if (AF32) af = afr[s];
    else      af = *(const short8*)(A + arow * K + (ke ^ ((arow & 7) << 3)));
    #pragma unroll
    for (int t = 0; t < 4; t++) {
      int bcol = 16 * t + c;
      short8 bf = *(const short8*)(B + bcol * K + (ke ^ ((bcol & 7) << 3)));
      acc[t] = __builtin_amdgcn_mfma_f32_16x16x32_bf16(af, bf, acc[t], 0, 0, 0);
    }
  }

  float av_s[4], av_d[4];
  #pragma unroll
  for (int t = 0; t < 4; t++) { av_s[t] = a_s[16 * t + c]; av_d[t] = a_d[16 * t + c]; }
  #pragma unroll
  for (int q = 0; q < 4; q++) {
    int row = n0 + 16 * w + g * 4 + q;
    bool ok = row < N;
    float rs = 0.f, rd = 0.f;
    #pragma unroll
    for (int t = 0; t < 4; t++) {
      float v = acc[t][q];
      if (ok) hb[(size_t)row * 64 + 16 * t + c] = tobf(v);
      rs += v * av_s[t]; rd += v * av_d[t];
    }
    #pragma unroll
    for (int off = 1; off < 16; off <<= 1) {
      rs += __shfl_xor(rs, off, 64);
      rd += __shfl_xor(rd, off, 64);
    }
    if (ok && c == 0) { asb[row] = rs; adb[row] = rd; }
  }
}

// ---------- sparse: fused softmax + aggregation ----------
// 16-deep gather bursts: two issue blocks (no drain) + one wait+fmac block.
// Mixed asm/compiler vmcnt accounting is safe: vmcnt retires in issue order,
// each party waits with its own younger-load count, our block waits vmcnt(0).
__global__ void k_agg(const int* __restrict__ roff, const int* __restrict__ csr,
                      const float* __restrict__ asb, const float* __restrict__ adb,
                      const short* __restrict__ hb, const float* __restrict__ b,
                      float* __restrict__ out, short* __restrict__ outb,
                      int N, int relu, int hb_bytes) {
  union { const short* p; unsigned u[2]; } up; up.p = hb;
  int4v rsrc;
  rsrc[0] = (int)up.u[0];
  rsrc[1] = (int)(up.u[1] & 0xffffu);   // base hi16, stride=0
  rsrc[2] = hb_bytes;                    // num_records (bytes)
  rsrc[3] = 0x00020000;                  // raw dword access
  int lane = threadIdx.x & 63;
  unsigned lane2 = (unsigned)lane * 2u;
  int wid = blockIdx.x * (blockDim.x >> 6) + (threadIdx.x >> 6);
  int nw = gridDim.x * (blockDim.x >> 6);
  float bv = b[lane];
  // d16_hi destinations: low halves zeroed once; loads write hi half only.
  float h0 = 0.f, h1 = 0.f, h2 = 0.f, h3 = 0.f, h4 = 0.f, h5 = 0.f, h6 = 0.f, h7 = 0.f;
  float h8 = 0.f, h9 = 0.f, hA = 0.f, hB = 0.f, hC = 0.f, hD = 0.f, hE = 0.f, hF = 0.f;
  for (int n = wid; n < N; n += nw) {
    int r0 = roff[n], r1 = roff[n + 1];
    float adn = adb[n];
    float acc = 0.f, denl = 0.f;
    for (int base = r0; base < r1; base += 64) {
      int cnt = min(64, r1 - base);
      int s128 = 0; float e = 0.f;
      if (lane < cnt) {
        s128 = csr[base + lane];          // byte offset src*128
        float l = asb[s128 >> 7] + adn;
        l = fmaxf(l, 0.2f * l);
        e = __expf(l);
      }
      denl += e;
      for (int j = 0; j < cnt; j += 16) {
        unsigned o0, o1, o2, o3, o4, o5, o6, o7;
        unsigned so, se, sj;
        // issue loads 0-7 (no drain)
        asm volatile(
          "s_mov_b32 %[sj], %[j]\n\t"
          "v_readlane_b32 %[so], %[vs], %[sj]\n\t"
          "v_add_u32 %[o0], %[so], %[vl]\n\t"
          "buffer_load_short_d16_hi %[h0], %[o0], %[rs], 0 offen\n\t"
          "s_add_u32 %[sj], %[sj], 1\n\t"
          "v_readlane_b32 %[so], %[vs], %[sj]\n\t"
          "v_add_u32 %[o1], %[so], %[vl]\n\t"
          "buffer_load_short_d16_hi %[h1], %[o1], %[rs], 0 offen\n\t"
          "s_add_u32 %[sj], %[sj], 1\n\t"
          "v_readlane_b32 %[so], %[vs], %[sj]\n\t"
          "v_add_u32 %[o2], %[so], %[vl]\n\t"
          "buffer_load_short_d16_hi %[h2], %[o2], %[rs], 0 offen\n\t"
          "s_add_u32 %[sj], %[sj], 1\n\t"
          "v_readlane_b32 %[so], %[vs], %[sj]\n\t"
          "v_add_u32 %[o3], %[so], %[vl]\n\t"
          "buffer_load_short_d16_hi %[h3], %[o3], %[rs], 0 offen\n\t"
          "s_add_u32 %[sj], %[sj], 1\n\t"
          "v_readlane_b32 %[so], %[vs], %[sj]\n\t"
          "v_add_u32 %[o4], %[so], %[vl]\n\t"
          "buffer_load_short_d16_hi %[h4], %[o4], %[rs], 0 offen\n\t"
          "s_add_u32 %[sj], %[sj], 1\n\t"
          "v_readlane_b32 %[so], %[vs], %[sj]\n\t"
          "v_add_u32 %[o5], %[so], %[vl]\n\t"
          "buffer_load_short_d16_hi %[h5], %[o5], %[rs], 0 offen\n\t"
          "s_add_u32 %[sj], %[sj], 1\n\t"
          "v_readlane_b32 %[so], %[vs], %[sj]\n\t"
          "v_add_u32 %[o6], %[so], %[vl]\n\t"
          "buffer_load_short_d16_hi %[h6], %[o6], %[rs], 0 offen\n\t"
          "s_add_u32 %[sj], %[sj], 1\n\t"
          "v_readlane_b32 %[so], %[vs], %[sj]\n\t"
          "v_add_u32 %[o7], %[so], %[vl]\n\t"
          "buffer_load_short_d16_hi %[h7], %[o7], %[rs], 0 offen\n\t"
          : [h0]"+v"(h0), [h1]"+v"(h1), [h2]"+v"(h2), [h3]"+v"(h3),
            [h4]"+v"(h4), [h5]"+v"(h5), [h6]"+v"(h6), [h7]"+v"(h7),
            [o0]"=&v"(o0), [o1]"=&v"(o1), [o2]"=&v"(o2), [o3]"=&v"(o3),
            [o4]"=&v"(o4), [o5]"=&v"(o5), [o6]"=&v"(o6), [o7]"=&v"(o7),
            [so]"=&s"(so), [sj]"=&s"(sj)
          : [vs]"v"(s128), [j]"s"(j), [vl]"v"(lane2), [rs]"s"(rsrc));
        // issue loads 8-15 (no drain)
        asm volatile(
          "s_mov_b32 %[sj], %[j]\n\t"
          "v_readlane_b32 %[so], %[vs], %[sj]\n\t"
          "v_add_u32 %[o0], %[so], %[vl]\n\t"
          "buffer_load_short_d16_hi %[h0], %[o0], %[rs], 0 offen\n\t"
          "s_add_u32 %[sj], %[sj], 1\n\t"
          "v_readlane_b32 %[so], %[vs], %[sj]\n\t"
          "v_add_u32 %[o1], %[so], %[vl]\n\t"
          "buffer_load_short_d16_hi %[h1], %[o1], %[rs], 0 offen\n\t"
          "s_add_u32 %[sj], %[sj], 1\n\t"
          "v_readlane_b32 %[so], %[vs], %[sj]\n\t"
          "v_add_u32 %[o2], %[so], %[vl]\n\t"
          "buffer_load_short_d16_hi %[h2], %[o2], %[rs], 0 offen\n\t"
          "s_add_u32 %[sj], %[sj], 1\n\t"
          "v_readlane_b32 %[so], %[vs], %[sj]\n\t"
          "v_add_u32 %[o3], %[so], %[vl]\n\t"
          "buffer_load_short_d16_hi %[h3], %[o3], %[rs], 0 offen\n\t"
          "s_add_u32 %[sj], %[sj], 1\n\t"
          "v_readlane_b32 %[so], %[vs], %[sj]\n\t"
          "v_add_u32 %[o4], %[so], %[vl]\n\t"
          "buffer_load_short_d16_hi %[h4], %[o4], %[rs], 0 offen\n\t"
          "s_add_u32 %[sj], %[sj], 1\n\t"
          "v_readlane_b32 %[so], %[vs], %[sj]\n\t"
          "v_add_u32 %[o5], %[so], %[vl]\n\t"
          "buffer_load_short_d16_hi %[h5], %[o5], %[rs], 0 offen\n\t"
          "s_add_u32 %[sj], %[sj], 1\n\t"
          "v_readlane_b32 %[so], %[vs], %[sj]\n\t"
          "v_add_u32 %[o6], %[so], %[vl]\n\t"
          "buffer_load_short_d16_hi %[h6], %[o6], %[rs], 0 offen\n\t"
          "s_add_u32 %[sj], %[sj], 1\n\t"
          "v_readlane_b32 %[so], %[vs], %[sj]\n\t"
          "v_add_u32 %[o7], %[so], %[vl]\n\t"
          "buffer_load_short_d16_hi %[h7], %[o7], %[rs], 0 offen\n\t"
          : [h0]"+v"(h8), [h1]"+v"(h9), [h2]"+v"(hA), [h3]"+v"(hB),
            [h4]"+v"(hC), [h5]"+v"(hD), [h6]"+v"(hE), [h7]"+v"(hF),
            [o0]"=&v"(o0), [o1]"=&v"(o1), [o2]"=&v"(o2), [o3]"=&v"(o3),
            [o4]"=&v"(o4), [o5]"=&v"(o5), [o6]"=&v"(o6), [o7]"=&v"(o7),
            [so]"=&s"(so), [sj]"=&s"(sj)
          : [vs]"v"(s128), [j]"s"(j + 8), [vl]"v"(lane2), [rs]"s"(rsrc));
        // single drain + 16 fmacs
        asm volatile(
          "s_waitcnt vmcnt(0)\n\t"
          "s_mov_b32 %[sj], %[j]\n\t"
          "v_readlane_b32 %[se], %[ve], %[sj]\n\t"
          "v_fmac_f32 %[acc], %[se], %[h0]\n\t"
          "s_add_u32 %[sj], %[sj], 1\n\t"
          "v_readlane_b32 %[se], %[ve], %[sj]\n\t"
          "v_fmac_f32 %[acc], %[se], %[h1]\n\t"
          "s_add_u32 %[sj], %[sj], 1\n\t"
          "v_readlane_b32 %[se], %[ve], %[sj]\n\t"
          "v_fmac_f32 %[acc], %[se], %[h2]\n\t"
          "s_add_u32 %[sj], %[sj], 1\n\t"
          "v_readlane_b32 %[se], %[ve], %[sj]\n\t"
          "v_fmac_f32 %[acc], %[se], %[h3]\n\t"
          "s_add_u32 %[sj], %[sj], 1\n\t"
          "v_readlane_b32 %[se], %[ve], %[sj]\n\t"
          "v_fmac_f32 %[acc], %[se], %[h4]\n\t"
          "s_add_u32 %[sj], %[sj], 1\n\t"
          "v_readlane_b32 %[se], %[ve], %[sj]\n\t"
          "v_fmac_f32 %[acc], %[se], %[h5]\n\t"
          "s_add_u32 %[sj], %[sj], 1\n\t"
          "v_readlane_b32 %[se], %[ve], %[sj]\n\t"
          "v_fmac_f32 %[acc], %[se], %[h6]\n\t"
          "s_add_u32 %[sj], %[sj], 1\n\t"
          "v_readlane_b32 %[se], %[ve], %[sj]\n\t"
          "v_fmac_f32 %[acc], %[se], %[h7]\n\t"
          "s_add_u32 %[sj], %[sj], 1\n\t"
          "v_readlane_b32 %[se], %[ve], %[sj]\n\t"
          "v_fmac_f32 %[acc], %[se], %[h8]\n\t"
          "s_add_u32 %[sj], %[sj], 1\n\t"
          "v_readlane_b32 %[se], %[ve], %[sj]\n\t"
          "v_fmac_f32 %[acc], %[se], %[h9]\n\t"
          "s_add_u32 %[sj], %[sj], 1\n\t"
          "v_readlane_b32 %[se], %[ve], %[sj]\n\t"
          "v_fmac_f32 %[acc], %[se], %[hA]\n\t"
          "s_add_u32 %[sj], %[sj], 1\n\t"
          "v_readlane_b32 %[se], %[ve], %[sj]\n\t"
          "v_fmac_f32 %[acc], %[se], %[hB]\n\t"
          "s_add_u32 %[sj], %[sj], 1\n\t"
          "v_readlane_b32 %[se], %[ve], %[sj]\n\t"
          "v_fmac_f32 %[acc], %[se], %[hC]\n\t"
          "s_add_u32 %[sj], %[sj], 1\n\t"
          "v_readlane_b32 %[se], %[ve], %[sj]\n\t"
          "v_fmac_f32 %[acc], %[se], %[hD]\n\t"
          "s_add_u32 %[sj], %[sj], 1\n\t"
          "v_readlane_b32 %[se], %[ve], %[sj]\n\t"
          "v_fmac_f32 %[acc], %[se], %[hE]\n\t"
          "s_add_u32 %[sj], %[sj], 1\n\t"
          "v_readlane_b32 %[se], %[ve], %[sj]\n\t"
          "v_fmac_f32 %[acc], %[se], %[hF]\n\t"
          : [acc]"+v"(acc), [se]"=&s"(se), [sj]"=&s"(sj)
          : [ve]"v"(e), [j]"s"(j),
            [h0]"v"(h0), [h1]"v"(h1), [h2]"v"(h2), [h3]"v"(h3),
            [h4]"v"(h4), [h5]"v"(h5), [h6]"v"(h6), [h7]"v"(h7),
            [h8]"v"(h8), [h9]"v"(h9), [hA]"v"(hA), [hB]"v"(hB),
            [hC]"v"(hC), [hD]"v"(hD), [hE]"v"(hE), [hF]"v"(hF));
      }
    }
    float den = denl;
    #pragma unroll
    for (int off = 32; off; off >>= 1) den += __shfl_xor(den, off, 64);
    float o = acc / (den + 1e-16f) + bv;
    if (relu) o = fmaxf(o, 0.f);
    out[(size_t)n * DHID + lane] = o;
    if (outb) outb[(size_t)n * DHID + (lane ^ ((n & 7) << 3))] = tobf(o);
  }
}

extern "C" void kernel_launch(void* const* d_in, const int* in_sizes, int n_in,
                              void* d_out, int out_size, void* d_ws, size_t ws_size,
                              hipStream_t stream) {
  const float* x   = (const float*)d_in[0];
  const int*   ei  = (const int*)d_in[1];
  const float* W1  = (const float*)d_in[2];
  const float* as1 = (const float*)d_in[3];
  const float* ad1 = (const float*)d_in[4];
  const float* b1  = (const float*)d_in[5];
  const float* W2  = (const float*)d_in[6];
  const float* as2 = (const float*)d_in[7];
  const float* ad2 = (const float*)d_in[8];
  const float* b2  = (const float*)d_in[9];

  int N = in_sizes[0] / 128;
  int E = in_sizes[1] / 2;
  const int* srcp = ei;
  const int* dstp = ei + E;

  float* emb  = (float*)d_out;
  float* out2 = emb + (size_t)N * DHID;

  char* w = (char*)d_ws;
  auto alloc = [&](size_t bytes) { char* p = w; w += (bytes + 255) & ~(size_t)255; return p; };
  int NR = ((N + 63) / 64) * 64;
  int* roff = (int*)alloc((size_t)(N + 1) * 4);
  int* csr  = (int*)alloc((size_t)(E + N) * 4);
  int* bsum = (int*)alloc(2048);
  char* scr0 = alloc((size_t)NR * 128 * 2);   // bkt, later eb
  short* hb = (short*)alloc((size_t)NR * 64 * 2);
  float* asb = (float*)alloc((size_t)N * 4);
  float* adb = (float*)alloc((size_t)N * 4);
  short* wt1 = (short*)alloc(64 * 128 * 2);
  short* wt2 = (short*)alloc(64 * 64 * 2);
  short* eb = (short*)scr0;       // overlay: layer-2 A input (written by agg1)
  int* bkt  = (int*)scr0;         // overlay: buckets dead before agg1 writes eb
  int* bcnt = (int*)hb;           // overlay: hb dead until mgemm1

  int nsb = (N + SUBSZ - 1) >> SUBSH;          // 196 sub-buckets
  int cap = E / nsb + 4096;                    // per-sub-bucket capacity (ints)
  int hb_bytes = NR * 128;

  int nb = (N + 1023) / 1024;
  int NBLK = (N + 63) / 64;

  hipMemsetAsync(bcnt, 0, (size_t)nsb * 4, stream);
  k_bucket<<<(E + EB - 1) / EB, 256, 0, stream>>>(srcp, dstp, bkt, bcnt, E, nsb, cap);
  k_count<<<nsb, 256, 0, stream>>>(bkt, bcnt, roff, N, cap);
  k_scan_block<<<nb, 256, 0, stream>>>(roff, N, bsum);
  k_scan_mid<<<1, 64, 0, stream>>>(bsum, nb);
  k_scan_add<<<(N + 255) / 256, 256, 0, stream>>>(roff, N, bsum, nb);
  k_place<<<nsb, 256, 0, stream>>>(bkt, bcnt, roff, csr, N, cap);

  k_prep<<<32, 256, 0, stream>>>(W1, wt1, 128);
  k_prep<<<32, 256, 0, stream>>>(W2, wt2, 64);

  k_mgemm<128, 1><<<NBLK, 256, 0, stream>>>(x, nullptr, wt1, as1, ad1, hb, asb, adb, N);
  k_agg<<<2048, 256, 0, stream>>>(roff, csr, asb, adb, hb, b1, emb, eb, N, 1, hb_bytes);
  k_mgemm<64, 0><<<NBLK, 256, 0, stream>>>(nullptr, eb, wt2, as2, ad2, hb, asb, adb, N);
  k_agg<<<2048, 256, 0, stream>>>(roff, csr, asb, adb, hb, b2, out2, (short*)nullptr, N, 0, hb_bytes);
}

// Round 11
// 184.030 us; speedup vs baseline: 1.8921x; 1.0373x over previous
//
#include <hip/hip_runtime.h>
#include <hip/hip_bf16.h>

#define DHID 64
#define SUBSH 9
#define SUBSZ (1 << SUBSH)     // 512 dst nodes per sub-bucket
#define PCAP 16384             // LDS staging cap (ints) in k_place
#define EB 4096                // edges per block in k_bucket
typedef __attribute__((ext_vector_type(8))) short short8;
typedef __attribute__((ext_vector_type(4))) float f32x4;

static __device__ __forceinline__ short tobf(float f) {
  __hip_bfloat16 h = __float2bfloat16(f);
  return *reinterpret_cast<short*>(&h);
}

// ---------- CSR build ----------
__global__ void k_bucket(const int* __restrict__ src, const int* __restrict__ dst,
                         int* __restrict__ bkt, int* __restrict__ bcnt,
                         int E, int nsb, int cap) {
  __shared__ int lcnt[256];
  __shared__ int lbase[256];
  int tid = threadIdx.x;
  int c0 = blockIdx.x * EB;
  if (c0 >= E) return;
  for (int i = tid; i < nsb; i += 256) lcnt[i] = 0;
  __syncthreads();
  int wloc[16], uloc[16];
  #pragma unroll
  for (int k = 0; k < 16; k++) {
    int i = c0 + tid + k * 256;
    if (i < E) {
      int d = dst[i];
      int w = d >> SUBSH;
      wloc[k] = w;
      uloc[k] = (src[i] << SUBSH) | (d & (SUBSZ - 1));
      atomicAdd(&lcnt[w], 1);
    } else wloc[k] = -1;
  }
  __syncthreads();
  for (int i = tid; i < nsb; i += 256) lbase[i] = atomicAdd(&bcnt[i], lcnt[i]);
  __syncthreads();
  for (int i = tid; i < nsb; i += 256) lcnt[i] = 0;   // reuse as local rank
  __syncthreads();
  #pragma unroll
  for (int k = 0; k < 16; k++) {
    int w = wloc[k];
    if (w >= 0) {
      int r = atomicAdd(&lcnt[w], 1);
      bkt[(size_t)w * cap + lbase[w] + r] = uloc[k];
    }
  }
}

__global__ void k_count(const int* __restrict__ bkt, const int* __restrict__ bcnt,
                        int* __restrict__ roff, int N, int cap) {
  __shared__ int h[SUBSZ];
  int sb = blockIdx.x, tid = threadIdx.x;
  for (int j = tid; j < SUBSZ; j += 256) h[j] = 1;   // self-loop pre-count
  __syncthreads();
  int n = bcnt[sb];
  const int* b = bkt + (size_t)sb * cap;
  for (int i = tid; i < n; i += 256) atomicAdd(&h[b[i] & (SUBSZ - 1)], 1);
  __syncthreads();
  int d0 = sb << SUBSH, d1 = min(N, d0 + SUBSZ);
  for (int j = tid; j < d1 - d0; j += 256) roff[d0 + j] = h[j];
}

__global__ void k_scan_block(int* __restrict__ buf, int n, int* __restrict__ bsum) {
  __shared__ int lds[256];
  int tid = threadIdx.x;
  int base = blockIdx.x * 1024 + tid * 4;
  int a0 = (base + 0) < n ? buf[base + 0] : 0;
  int a1 = (base + 1) < n ? buf[base + 1] : 0;
  int a2 = (base + 2) < n ? buf[base + 2] : 0;
  int a3 = (base + 3) < n ? buf[base + 3] : 0;
  int s = a0 + a1 + a2 + a3;
  lds[tid] = s; __syncthreads();
  for (int off = 1; off < 256; off <<= 1) {
    int t = (tid >= off) ? lds[tid - off] : 0;
    __syncthreads();
    lds[tid] += t;
    __syncthreads();
  }
  int excl = lds[tid] - s;
  if ((base + 0) < n) buf[base + 0] = excl; excl += a0;
  if ((base + 1) < n) buf[base + 1] = excl; excl += a1;
  if ((base + 2) < n) buf[base + 2] = excl; excl += a2;
  if ((base + 3) < n) buf[base + 3] = excl;
  if (tid == 255) bsum[blockIdx.x] = lds[255];
}

__global__ void k_scan_mid(int* __restrict__ bsum, int nb) {
  int lane = threadIdx.x;
  int v0 = (lane < nb) ? bsum[lane] : 0;
  #pragma unroll
  for (int off = 1; off < 64; off <<= 1) { int t = __shfl_up(v0, off, 64); if (lane >= off) v0 += t; }
  int v1 = (64 + lane) < nb ? bsum[64 + lane] : 0;
  #pragma unroll
  for (int off = 1; off < 64; off <<= 1) { int t = __shfl_up(v1, off, 64); if (lane >= off) v1 += t; }
  v1 += __shfl(v0, 63, 64);
  if (lane < nb) bsum[lane] = v0;
  if ((64 + lane) < nb) bsum[64 + lane] = v1;
}

__global__ void k_scan_add(int* __restrict__ buf, int n, const int* __restrict__ bsum, int nb) {
  int i = blockIdx.x * blockDim.x + threadIdx.x;
  if (i < n) { int c = i >> 10; if (c > 0) buf[i] += bsum[c - 1]; }
  if (i == 0) buf[n] = bsum[nb - 1];
}

// pass 3: LDS counting-sort placement; csr stores BYTE offsets (src*128)
__global__ void k_place(const int* __restrict__ bkt, const int* __restrict__ bcnt,
                        const int* __restrict__ roff, int* __restrict__ csr,
                        int N, int cap) {
  __shared__ int roff_l[SUBSZ + 1];
  __shared__ int lcnt[SUBSZ];
  __shared__ int stage[PCAP];
  int sb = blockIdx.x, tid = threadIdx.x;
  int d0 = sb << SUBSH;
  int d1 = min(N, d0 + SUBSZ);
  int nn = d1 - d0;
  for (int j = tid; j <= nn; j += 256) roff_l[j] = roff[d0 + j];
  for (int j = tid; j < SUBSZ; j += 256) lcnt[j] = 0;
  __syncthreads();
  int base = roff_l[0];
  int span = roff_l[nn] - base;
  int nE = bcnt[sb];
  const int* b = bkt + (size_t)sb * cap;
  if (span <= PCAP) {
    for (int d = tid; d < nn; d += 256) stage[roff_l[d] - base] = (d0 + d) << 7;  // self-loop
    for (int i = tid; i < nE; i += 256) {
      int u = b[i];
      int dl = u & (SUBSZ - 1);
      int rk = 1 + atomicAdd(&lcnt[dl], 1);
      stage[roff_l[dl] - base + rk] = (u >> SUBSH) << 7;
    }
    __syncthreads();
    for (int j = tid; j < span; j += 256) csr[base + j] = stage[j];
  } else {  // correctness fallback (never for random graphs)
    for (int d = tid; d < nn; d += 256) csr[roff_l[d]] = (d0 + d) << 7;
    for (int i = tid; i < nE; i += 256) {
      int u = b[i];
      int dl = u & (SUBSZ - 1);
      int rk = 1 + atomicAdd(&lcnt[dl], 1);
      csr[roff_l[dl] + rk] = (u >> SUBSH) << 7;
    }
  }
}

// ---------- prep: W [K][64] -> Wt bf16 [64][K], XOR-swizzled (grid-parallel) ----------
__global__ void k_prep(const float* __restrict__ W, short* __restrict__ wt, int K) {
  int stride = gridDim.x * blockDim.x;
  for (int e = blockIdx.x * blockDim.x + threadIdx.x; e < 64 * K; e += stride) {
    int k = e >> 6, c = e & 63;                        // coalesced read W[k][c]
    wt[c * K + (k ^ ((c & 7) << 3))] = tobf(W[e]);
  }
}

// ---------- MFMA gemm ----------
// AF32=1: A loaded per-lane from fp32 x, converted in-reg (no LDS, no cvt pass).
// AF32=0: A (bf16, pre-swizzled) staged to LDS via global_load_lds.
template<int K, int AF32>
__launch_bounds__(256)
__global__ void k_mgemm(const float* __restrict__ xf, const short* __restrict__ xb,
                        const short* __restrict__ wt,
                        const float* __restrict__ a_s, const float* __restrict__ a_d,
                        short* __restrict__ hb, float* __restrict__ asb,
                        float* __restrict__ adb, int N) {
  constexpr int ASZ = 64 * K * 2;          // bytes of one bf16 tile
  __shared__ __align__(16) short lds[(AF32 ? 1 : 2) * 64 * K];
  int tid = threadIdx.x;
  int n0 = blockIdx.x * 64;

  if (AF32) {
    const char* gb = (const char*)wt;
    #pragma unroll
    for (int j = 0; j < ASZ / 4096; j++) {
      int d = j * 4096 + tid * 16;
      __builtin_amdgcn_global_load_lds(
          (__attribute__((address_space(1))) const void*)(gb + d),
          (__attribute__((address_space(3))) void*)((char*)lds + d), 16, 0, 0);
    }
  } else {
    const char* ga = (const char*)xb + (size_t)n0 * (K * 2);
    const char* gb = (const char*)wt;
    #pragma unroll
    for (int j = 0; j < (2 * ASZ) / 4096; j++) {
      int d = j * 4096 + tid * 16;
      const char* src = (d < ASZ) ? (ga + d) : (gb + (d - ASZ));
      __builtin_amdgcn_global_load_lds(
          (__attribute__((address_space(1))) const void*)src,
          (__attribute__((address_space(3))) void*)((char*)lds + d), 16, 0, 0);
    }
  }
  __syncthreads();

  int l = tid & 63, w = tid >> 6;
  int c = l & 15, g = l >> 4;
  const short* A = lds;
  const short* B = AF32 ? lds : lds + 64 * K;
  f32x4 acc[4];
  #pragma unroll
  for (int t = 0; t < 4; t++) acc[t] = (f32x4){0.f, 0.f, 0.f, 0.f};

  int arow = 16 * w + c;
  short8 afr[K / 32];
  if (AF32) {
    int row = n0 + arow;
    const float* xr = xf + (size_t)row * 128;
    bool okr = row < N;
    #pragma unroll
    for (int s = 0; s < K / 32; s++) {
      int ke = s * 32 + g * 8;
      float4 u0 = make_float4(0.f, 0.f, 0.f, 0.f), u1 = u0;
      if (okr) { u0 = *(const float4*)(xr + ke); u1 = *(const float4*)(xr + ke + 4); }
      short8 af;
      af[0] = tobf(u0.x); af[1] = tobf(u0.y); af[2] = tobf(u0.z); af[3] = tobf(u0.w);
      af[4] = tobf(u1.x); af[5] = tobf(u1.y); af[6] = tobf(u1.z); af[7] = tobf(u1.w);
      afr[s] = af;
    }
  }

  #pragma unroll
  for (int s = 0; s < K / 32; s++) {
    int ke = s * 32 + g * 8;
    short8 af;
    if (AF32) af = afr[s];
    else      af = *(const short8*)(A + arow * K + (ke ^ ((arow & 7) << 3)));
    #pragma unroll
    for (int t = 0; t < 4; t++) {
      int bcol = 16 * t + c;
      short8 bf = *(const short8*)(B + bcol * K + (ke ^ ((bcol & 7) << 3)));
      acc[t] = __builtin_amdgcn_mfma_f32_16x16x32_bf16(af, bf, acc[t], 0, 0, 0);
    }
  }

  float av_s[4], av_d[4];
  #pragma unroll
  for (int t = 0; t < 4; t++) { av_s[t] = a_s[16 * t + c]; av_d[t] = a_d[16 * t + c]; }
  #pragma unroll
  for (int q = 0; q < 4; q++) {
    int row = n0 + 16 * w + g * 4 + q;
    bool ok = row < N;
    float rs = 0.f, rd = 0.f;
    #pragma unroll
    for (int t = 0; t < 4; t++) {
      float v = acc[t][q];
      if (ok) hb[(size_t)row * 64 + 16 * t + c] = tobf(v);
      rs += v * av_s[t]; rd += v * av_d[t];
    }
    #pragma unroll
    for (int off = 1; off < 16; off <<= 1) {
      rs += __shfl_xor(rs, off, 64);
      rd += __shfl_xor(rd, off, 64);
    }
    if (ok && c == 0) { asb[row] = rs; adb[row] = rd; }
  }
}

// ---------- sparse: fused softmax + aggregation ----------
// Phase 2 re-shaped: 16 lanes per h row (4 bf16 cols/lane via dwordx2), 4 edges
// per wave-op. Weights/offsets broadcast to 16-lane groups via ds_bpermute.
// ~2.5 VALU + 0.25 VMEM per edge (vs ~6 VALU + 1 VMEM in the readlane form).
__global__ void k_agg(const int* __restrict__ roff, const int* __restrict__ csr,
                      const float* __restrict__ asb, const float* __restrict__ adb,
                      const short* __restrict__ hb, const float* __restrict__ b,
                      float* __restrict__ out, short* __restrict__ outb,
                      int N, int relu) {
  const char* hbase = (const char*)hb;
  int lane = threadIdx.x & 63;
  int colb = (lane & 15) * 8;            // byte offset of this lane's 4 cols
  int L = lane & 15;
  int wid = blockIdx.x * (blockDim.x >> 6) + (threadIdx.x >> 6);
  int nw = gridDim.x * (blockDim.x >> 6);
  float4 bv4 = ((const float4*)b)[L];
  for (int n = wid; n < N; n += nw) {
    int r0 = roff[n], r1 = roff[n + 1];
    float adn = adb[n];
    float a0 = 0.f, a1 = 0.f, a2 = 0.f, a3 = 0.f, denl = 0.f;
    for (int base = r0; base < r1; base += 64) {
      int cnt = min(64, r1 - base);
      int s128 = 0; float e = 0.f;
      if (lane < cnt) {
        s128 = csr[base + lane];          // byte offset src*128
        float l = asb[s128 >> 7] + adn;
        l = fmaxf(l, 0.2f * l);
        e = __expf(l);
      }
      denl += e;
      int cntUp = (cnt + 3) & ~3;
      int addrv = (lane >> 4) << 2;       // bpermute byte-addr: group g -> edge j+g
      #pragma unroll 2
      for (int j = 0; j < cntUp; j += 4) {
        int sofs = __builtin_amdgcn_ds_bpermute(addrv, s128);
        int ewi  = __builtin_amdgcn_ds_bpermute(addrv, (int)__float_as_uint(e));
        addrv += 16;
        float ew = __uint_as_float((unsigned)ewi);
        uint2 u = *(const uint2*)(hbase + (unsigned)(sofs + colb));
        a0 = fmaf(__uint_as_float(u.x << 16), ew, a0);
        a1 = fmaf(__uint_as_float(u.x & 0xFFFF0000u), ew, a1);
        a2 = fmaf(__uint_as_float(u.y << 16), ew, a2);
        a3 = fmaf(__uint_as_float(u.y & 0xFFFF0000u), ew, a3);
      }
    }
    // combine the 4 16-lane groups (each holds a disjoint edge subset)
    #pragma unroll
    for (int off = 16; off <= 32; off <<= 1) {
      a0 += __shfl_xor(a0, off, 64); a1 += __shfl_xor(a1, off, 64);
      a2 += __shfl_xor(a2, off, 64); a3 += __shfl_xor(a3, off, 64);
    }
    float den = denl;
    #pragma unroll
    for (int off = 32; off; off >>= 1) den += __shfl_xor(den, off, 64);
    float inv = 1.f / (den + 1e-16f);
    if (lane < 16) {
      float4 o;
      o.x = fmaf(a0, inv, bv4.x); o.y = fmaf(a1, inv, bv4.y);
      o.z = fmaf(a2, inv, bv4.z); o.w = fmaf(a3, inv, bv4.w);
      if (relu) {
        o.x = fmaxf(o.x, 0.f); o.y = fmaxf(o.y, 0.f);
        o.z = fmaxf(o.z, 0.f); o.w = fmaxf(o.w, 0.f);
      }
      ((float4*)(out + (size_t)n * DHID))[L] = o;
      if (outb) {
        // col swizzle c^=((n&7)<<3) touches only bits 3-5 -> short4 grain moves
        // as a unit: L' = L ^ ((n&7)<<1)
        short4 ob = make_short4(tobf(o.x), tobf(o.y), tobf(o.z), tobf(o.w));
        ((short4*)(outb + (size_t)n * DHID))[L ^ ((n & 7) << 1)] = ob;
      }
    }
  }
}

extern "C" void kernel_launch(void* const* d_in, const int* in_sizes, int n_in,
                              void* d_out, int out_size, void* d_ws, size_t ws_size,
                              hipStream_t stream) {
  const float* x   = (const float*)d_in[0];
  const int*   ei  = (const int*)d_in[1];
  const float* W1  = (const float*)d_in[2];
  const float* as1 = (const float*)d_in[3];
  const float* ad1 = (const float*)d_in[4];
  const float* b1  = (const float*)d_in[5];
  const float* W2  = (const float*)d_in[6];
  const float* as2 = (const float*)d_in[7];
  const float* ad2 = (const float*)d_in[8];
  const float* b2  = (const float*)d_in[9];

  int N = in_sizes[0] / 128;
  int E = in_sizes[1] / 2;
  const int* srcp = ei;
  const int* dstp = ei + E;

  float* emb  = (float*)d_out;
  float* out2 = emb + (size_t)N * DHID;

  char* w = (char*)d_ws;
  auto alloc = [&](size_t bytes) { char* p = w; w += (bytes + 255) & ~(size_t)255; return p; };
  int NR = ((N + 63) / 64) * 64;
  int* roff = (int*)alloc((size_t)(N + 1) * 4);
  int* csr  = (int*)alloc((size_t)(E + N) * 4);
  int* bsum = (int*)alloc(2048);
  char* scr0 = alloc((size_t)NR * 128 * 2);   // bkt, later eb
  short* hb = (short*)alloc((size_t)NR * 64 * 2);
  float* asb = (float*)alloc((size_t)N * 4);
  float* adb = (float*)alloc((size_t)N * 4);
  short* wt1 = (short*)alloc(64 * 128 * 2);
  short* wt2 = (short*)alloc(64 * 64 * 2);
  short* eb = (short*)scr0;       // overlay: layer-2 A input (written by agg1)
  int* bkt  = (int*)scr0;         // overlay: buckets dead before agg1 writes eb
  int* bcnt = (int*)hb;           // overlay: hb dead until mgemm1

  int nsb = (N + SUBSZ - 1) >> SUBSH;          // sub-buckets
  int cap = E / nsb + 4096;                    // per-sub-bucket capacity (ints)

  int nb = (N + 1023) / 1024;
  int NBLK = (N + 63) / 64;

  hipMemsetAsync(bcnt, 0, (size_t)nsb * 4, stream);
  k_bucket<<<(E + EB - 1) / EB, 256, 0, stream>>>(srcp, dstp, bkt, bcnt, E, nsb, cap);
  k_count<<<nsb, 256, 0, stream>>>(bkt, bcnt, roff, N, cap);
  k_scan_block<<<nb, 256, 0, stream>>>(roff, N, bsum);
  k_scan_mid<<<1, 64, 0, stream>>>(bsum, nb);
  k_scan_add<<<(N + 255) / 256, 256, 0, stream>>>(roff, N, bsum, nb);
  k_place<<<nsb, 256, 0, stream>>>(bkt, bcnt, roff, csr, N, cap);

  k_prep<<<32, 256, 0, stream>>>(W1, wt1, 128);
  k_prep<<<32, 256, 0, stream>>>(W2, wt2, 64);

  k_mgemm<128, 1><<<NBLK, 256, 0, stream>>>(x, nullptr, wt1, as1, ad1, hb, asb, adb, N);
  k_agg<<<2048, 256, 0, stream>>>(roff, csr, asb, adb, hb, b1, emb, eb, N, 1);
  k_mgemm<64, 0><<<NBLK, 256, 0, stream>>>(nullptr, eb, wt2, as2, ad2, hb, asb, adb, N);
  k_agg<<<2048, 256, 0, stream>>>(roff, csr, asb, adb, hb, b2, out2, (short*)nullptr, N, 0);
}

// Round 12
// 180.503 us; speedup vs baseline: 1.9291x; 1.0195x over previous
//
#include <hip/hip_runtime.h>
#include <hip/hip_bf16.h>

#define DHID 64
#define SUBSH 9
#define SUBSZ (1 << SUBSH)     // 512 dst nodes per sub-bucket
#define PCAP 16384             // LDS staging cap (ints) in k_place
#define EB 2048                // edges per block in bucket pass
typedef __attribute__((ext_vector_type(8))) short short8;
typedef __attribute__((ext_vector_type(4))) float f32x4;

static __device__ __forceinline__ short tobf(float f) {
  __hip_bfloat16 h = __float2bfloat16(f);
  return *reinterpret_cast<short*>(&h);
}

// ---------- fused A: edge bucket partition (blocks < nbkt) || layer-1 MFMA gemm ----------
// bucket: single-pass local rank (one LDS atomic per edge), payload (src<<9)|(d&511).
// mgemm1: A per-lane from fp32 x (in-reg bf16 convert); B = W1 self-converted
//+ XOR-swizzled into LDS by each block (no prep kernel, no dependencies).
__global__ __launch_bounds__(256)
void k_fusedA(const int* __restrict__ src, const int* __restrict__ dst,
              int* __restrict__ bkt, int* __restrict__ bcnt,
              int E, int nsb, int cap, int nbkt,
              const float* __restrict__ xf, const float* __restrict__ W1,
              const float* __restrict__ a_s, const float* __restrict__ a_d,
              short* __restrict__ hb, float* __restrict__ asb,
              float* __restrict__ adb, int N) {
  __shared__ int lcnt[256];
  __shared__ int lbase[256];
  __shared__ __align__(16) short ldsB[64 * 128];
  int tid = threadIdx.x;
  if (blockIdx.x < nbkt) {
    // ---- bucket path ----
    int c0 = blockIdx.x * EB;
    for (int i = tid; i < nsb; i += 256) lcnt[i] = 0;
    __syncthreads();
    int wloc[8], uloc[8], rloc[8];
    #pragma unroll
    for (int k = 0; k < 8; k++) {
      int i = c0 + tid + k * 256;
      if (i < E) {
        int d = dst[i];
        int w = d >> SUBSH;
        wloc[k] = w;
        uloc[k] = (src[i] << SUBSH) | (d & (SUBSZ - 1));
        rloc[k] = atomicAdd(&lcnt[w], 1);
      } else wloc[k] = -1;
    }
    __syncthreads();
    for (int i = tid; i < nsb; i += 256) lbase[i] = atomicAdd(&bcnt[i], lcnt[i]);
    __syncthreads();
    #pragma unroll
    for (int k = 0; k < 8; k++) {
      int w = wloc[k];
      if (w >= 0) bkt[(size_t)w * cap + lbase[w] + rloc[k]] = uloc[k];
    }
    return;
  }
  // ---- mgemm1 path (K=128) ----
  int n0 = (blockIdx.x - nbkt) * 64;
  for (int e = tid; e < 128 * 64; e += 256) {
    int k = e >> 6, c = e & 63;                       // coalesced read W1[k][c]
    ldsB[c * 128 + (k ^ ((c & 7) << 3))] = tobf(W1[e]);
  }
  __syncthreads();

  int l = tid & 63, w = tid >> 6;
  int c = l & 15, g = l >> 4;
  f32x4 acc[4];
  #pragma unroll
  for (int t = 0; t < 4; t++) acc[t] = (f32x4){0.f, 0.f, 0.f, 0.f};

  int arow = 16 * w + c;
  int row0 = n0 + arow;
  const float* xr = xf + (size_t)row0 * 128;
  bool okr = row0 < N;
  short8 afr[4];
  #pragma unroll
  for (int s = 0; s < 4; s++) {
    int ke = s * 32 + g * 8;
    float4 u0 = make_float4(0.f, 0.f, 0.f, 0.f), u1 = u0;
    if (okr) { u0 = *(const float4*)(xr + ke); u1 = *(const float4*)(xr + ke + 4); }
    short8 af;
    af[0] = tobf(u0.x); af[1] = tobf(u0.y); af[2] = tobf(u0.z); af[3] = tobf(u0.w);
    af[4] = tobf(u1.x); af[5] = tobf(u1.y); af[6] = tobf(u1.z); af[7] = tobf(u1.w);
    afr[s] = af;
  }
  #pragma unroll
  for (int s = 0; s < 4; s++) {
    int ke = s * 32 + g * 8;
    #pragma unroll
    for (int t = 0; t < 4; t++) {
      int bcol = 16 * t + c;
      short8 bf = *(const short8*)(ldsB + bcol * 128 + (ke ^ ((bcol & 7) << 3)));
      acc[t] = __builtin_amdgcn_mfma_f32_16x16x32_bf16(afr[s], bf, acc[t], 0, 0, 0);
    }
  }
  float av_s[4], av_d[4];
  #pragma unroll
  for (int t = 0; t < 4; t++) { av_s[t] = a_s[16 * t + c]; av_d[t] = a_d[16 * t + c]; }
  #pragma unroll
  for (int q = 0; q < 4; q++) {
    int row = n0 + 16 * w + g * 4 + q;
    bool ok = row < N;
    float rs = 0.f, rd = 0.f;
    #pragma unroll
    for (int t = 0; t < 4; t++) {
      float v = acc[t][q];
      if (ok) hb[(size_t)row * 64 + 16 * t + c] = tobf(v);
      rs += v * av_s[t]; rd += v * av_d[t];
    }
    #pragma unroll
    for (int off = 1; off < 16; off <<= 1) {
      rs += __shfl_xor(rs, off, 64);
      rd += __shfl_xor(rd, off, 64);
    }
    if (ok && c == 0) { asb[row] = rs; adb[row] = rd; }
  }
}

// ---------- layer-2 MFMA gemm: A = eb (pre-swizzled bf16) via global_load_lds,
// B = W2 self-converted into LDS ----------
__global__ __launch_bounds__(256)
void k_mgemm2(const short* __restrict__ eb, const float* __restrict__ W2,
              const float* __restrict__ a_s, const float* __restrict__ a_d,
              short* __restrict__ hb, float* __restrict__ asb,
              float* __restrict__ adb, int N) {
  __shared__ __align__(16) short lds[64 * 64 * 2];   // A (8KB) + B (8KB)
  int tid = threadIdx.x;
  int n0 = blockIdx.x * 64;
  const char* ga = (const char*)eb + (size_t)n0 * 128;
  #pragma unroll
  for (int j = 0; j < 2; j++) {
    int d = j * 4096 + tid * 16;
    __builtin_amdgcn_global_load_lds(
        (__attribute__((address_space(1))) const void*)(ga + d),
        (__attribute__((address_space(3))) void*)((char*)lds + d), 16, 0, 0);
  }
  short* B = lds + 64 * 64;
  for (int e = tid; e < 64 * 64; e += 256) {
    int k = e >> 6, c = e & 63;
    B[c * 64 + (k ^ ((c & 7) << 3))] = tobf(W2[e]);
  }
  __syncthreads();

  int l = tid & 63, w = tid >> 6;
  int c = l & 15, g = l >> 4;
  const short* A = lds;
  f32x4 acc[4];
  #pragma unroll
  for (int t = 0; t < 4; t++) acc[t] = (f32x4){0.f, 0.f, 0.f, 0.f};
  int arow = 16 * w + c;
  #pragma unroll
  for (int s = 0; s < 2; s++) {
    int ke = s * 32 + g * 8;
    short8 af = *(const short8*)(A + arow * 64 + (ke ^ ((arow & 7) << 3)));
    #pragma unroll
    for (int t = 0; t < 4; t++) {
      int bcol = 16 * t + c;
      short8 bf = *(const short8*)(B + bcol * 64 + (ke ^ ((bcol & 7) << 3)));
      acc[t] = __builtin_amdgcn_mfma_f32_16x16x32_bf16(af, bf, acc[t], 0, 0, 0);
    }
  }
  float av_s[4], av_d[4];
  #pragma unroll
  for (int t = 0; t < 4; t++) { av_s[t] = a_s[16 * t + c]; av_d[t] = a_d[16 * t + c]; }
  #pragma unroll
  for (int q = 0; q < 4; q++) {
    int row = n0 + 16 * w + g * 4 + q;
    bool ok = row < N;
    float rs = 0.f, rd = 0.f;
    #pragma unroll
    for (int t = 0; t < 4; t++) {
      float v = acc[t][q];
      if (ok) hb[(size_t)row * 64 + 16 * t + c] = tobf(v);
      rs += v * av_s[t]; rd += v * av_d[t];
    }
    #pragma unroll
    for (int off = 1; off < 16; off <<= 1) {
      rs += __shfl_xor(rs, off, 64);
      rd += __shfl_xor(rd, off, 64);
    }
    if (ok && c == 0) { asb[row] = rs; adb[row] = rd; }
  }
}

// ---------- CSR: count / scan / place ----------
__global__ void k_count(const int* __restrict__ bkt, const int* __restrict__ bcnt,
                        int* __restrict__ roff, int N, int cap) {
  __shared__ int h[SUBSZ];
  int sb = blockIdx.x, tid = threadIdx.x;
  for (int j = tid; j < SUBSZ; j += 256) h[j] = 1;   // self-loop pre-count
  __syncthreads();
  int n = bcnt[sb];
  const int* b = bkt + (size_t)sb * cap;
  for (int i = tid; i < n; i += 256) atomicAdd(&h[b[i] & (SUBSZ - 1)], 1);
  __syncthreads();
  int d0 = sb << SUBSH, d1 = min(N, d0 + SUBSZ);
  for (int j = tid; j < d1 - d0; j += 256) roff[d0 + j] = h[j];
}

__global__ void k_scan_block(int* __restrict__ buf, int n, int* __restrict__ bsum) {
  __shared__ int lds[256];
  int tid = threadIdx.x;
  int base = blockIdx.x * 1024 + tid * 4;
  int a0 = (base + 0) < n ? buf[base + 0] : 0;
  int a1 = (base + 1) < n ? buf[base + 1] : 0;
  int a2 = (base + 2) < n ? buf[base + 2] : 0;
  int a3 = (base + 3) < n ? buf[base + 3] : 0;
  int s = a0 + a1 + a2 + a3;
  lds[tid] = s; __syncthreads();
  for (int off = 1; off < 256; off <<= 1) {
    int t = (tid >= off) ? lds[tid - off] : 0;
    __syncthreads();
    lds[tid] += t;
    __syncthreads();
  }
  int excl = lds[tid] - s;
  if ((base + 0) < n) buf[base + 0] = excl; excl += a0;
  if ((base + 1) < n) buf[base + 1] = excl; excl += a1;
  if ((base + 2) < n) buf[base + 2] = excl; excl += a2;
  if ((base + 3) < n) buf[base + 3] = excl;
  if (tid == 255) bsum[blockIdx.x] = lds[255];
}

__global__ void k_scan_mid(int* __restrict__ bsum, int nb) {
  int lane = threadIdx.x;
  int v0 = (lane < nb) ? bsum[lane] : 0;
  #pragma unroll
  for (int off = 1; off < 64; off <<= 1) { int t = __shfl_up(v0, off, 64); if (lane >= off) v0 += t; }
  int v1 = (64 + lane) < nb ? bsum[64 + lane] : 0;
  #pragma unroll
  for (int off = 1; off < 64; off <<= 1) { int t = __shfl_up(v1, off, 64); if (lane >= off) v1 += t; }
  v1 += __shfl(v0, 63, 64);
  if (lane < nb) bsum[lane] = v0;
  if ((64 + lane) < nb) bsum[64 + lane] = v1;
}

__global__ void k_scan_add(int* __restrict__ buf, int n, const int* __restrict__ bsum, int nb) {
  int i = blockIdx.x * blockDim.x + threadIdx.x;
  if (i < n) { int c = i >> 10; if (c > 0) buf[i] += bsum[c - 1]; }
  if (i == 0) buf[n] = bsum[nb - 1];
}

// LDS counting-sort placement; csr stores BYTE offsets (src*128)
__global__ void k_place(const int* __restrict__ bkt, const int* __restrict__ bcnt,
                        const int* __restrict__ roff, int* __restrict__ csr,
                        int N, int cap) {
  __shared__ int roff_l[SUBSZ + 1];
  __shared__ int lcnt[SUBSZ];
  __shared__ int stage[PCAP];
  int sb = blockIdx.x, tid = threadIdx.x;
  int d0 = sb << SUBSH;
  int d1 = min(N, d0 + SUBSZ);
  int nn = d1 - d0;
  for (int j = tid; j <= nn; j += 256) roff_l[j] = roff[d0 + j];
  for (int j = tid; j < SUBSZ; j += 256) lcnt[j] = 0;
  __syncthreads();
  int base = roff_l[0];
  int span = roff_l[nn] - base;
  int nE = bcnt[sb];
  const int* b = bkt + (size_t)sb * cap;
  if (span <= PCAP) {
    for (int d = tid; d < nn; d += 256) stage[roff_l[d] - base] = (d0 + d) << 7;  // self-loop
    for (int i = tid; i < nE; i += 256) {
      int u = b[i];
      int dl = u & (SUBSZ - 1);
      int rk = 1 + atomicAdd(&lcnt[dl], 1);
      stage[roff_l[dl] - base + rk] = (u >> SUBSH) << 7;
    }
    __syncthreads();
    for (int j = tid; j < span; j += 256) csr[base + j] = stage[j];
  } else {  // correctness fallback (never for random graphs)
    for (int d = tid; d < nn; d += 256) csr[roff_l[d]] = (d0 + d) << 7;
    for (int i = tid; i < nE; i += 256) {
      int u = b[i];
      int dl = u & (SUBSZ - 1);
      int rk = 1 + atomicAdd(&lcnt[dl], 1);
      csr[roff_l[dl] + rk] = (u >> SUBSH) << 7;
    }
  }
}

// ---------- sparse: fused softmax + aggregation ----------
// 16 lanes per h row (4 bf16 cols/lane via dwordx2), 4 edges per wave-op;
// weights/offsets broadcast to 16-lane groups via ds_bpermute.
__global__ void k_agg(const int* __restrict__ roff, const int* __restrict__ csr,
                      const float* __restrict__ asb, const float* __restrict__ adb,
                      const short* __restrict__ hb, const float* __restrict__ b,
                      float* __restrict__ out, short* __restrict__ outb,
                      int N, int relu) {
  const char* hbase = (const char*)hb;
  int lane = threadIdx.x & 63;
  int colb = (lane & 15) * 8;            // byte offset of this lane's 4 cols
  int L = lane & 15;
  int wid = blockIdx.x * (blockDim.x >> 6) + (threadIdx.x >> 6);
  int nw = gridDim.x * (blockDim.x >> 6);
  float4 bv4 = ((const float4*)b)[L];
  for (int n = wid; n < N; n += nw) {
    int r0 = roff[n], r1 = roff[n + 1];
    float adn = adb[n];
    float a0 = 0.f, a1 = 0.f, a2 = 0.f, a3 = 0.f, denl = 0.f;
    for (int base = r0; base < r1; base += 64) {
      int cnt = min(64, r1 - base);
      int s128 = 0; float e = 0.f;
      if (lane < cnt) {
        s128 = csr[base + lane];          // byte offset src*128
        float l = asb[s128 >> 7] + adn;
        l = fmaxf(l, 0.2f * l);
        e = __expf(l);
      }
      denl += e;
      int cntUp = (cnt + 3) & ~3;
      int addrv = (lane >> 4) << 2;       // bpermute byte-addr: group g -> edge j+g
      #pragma unroll 4
      for (int j = 0; j < cntUp; j += 4) {
        int sofs = __builtin_amdgcn_ds_bpermute(addrv, s128);
        int ewi  = __builtin_amdgcn_ds_bpermute(addrv, (int)__float_as_uint(e));
        addrv += 16;
        float ew = __uint_as_float((unsigned)ewi);
        uint2 u = *(const uint2*)(hbase + (unsigned)(sofs + colb));
        a0 = fmaf(__uint_as_float(u.x << 16), ew, a0);
        a1 = fmaf(__uint_as_float(u.x & 0xFFFF0000u), ew, a1);
        a2 = fmaf(__uint_as_float(u.y << 16), ew, a2);
        a3 = fmaf(__uint_as_float(u.y & 0xFFFF0000u), ew, a3);
      }
    }
    #pragma unroll
    for (int off = 16; off <= 32; off <<= 1) {
      a0 += __shfl_xor(a0, off, 64); a1 += __shfl_xor(a1, off, 64);
      a2 += __shfl_xor(a2, off, 64); a3 += __shfl_xor(a3, off, 64);
    }
    float den = denl;
    #pragma unroll
    for (int off = 32; off; off >>= 1) den += __shfl_xor(den, off, 64);
    float inv = 1.f / (den + 1e-16f);
    if (lane < 16) {
      float4 o;
      o.x = fmaf(a0, inv, bv4.x); o.y = fmaf(a1, inv, bv4.y);
      o.z = fmaf(a2, inv, bv4.z); o.w = fmaf(a3, inv, bv4.w);
      if (relu) {
        o.x = fmaxf(o.x, 0.f); o.y = fmaxf(o.y, 0.f);
        o.z = fmaxf(o.z, 0.f); o.w = fmaxf(o.w, 0.f);
      }
      ((float4*)(out + (size_t)n * DHID))[L] = o;
      if (outb) {
        // col swizzle c^=((n&7)<<3) touches only bits 3-5 -> short4 grain moves
        // as a unit: L' = L ^ ((n&7)<<1)
        short4 ob = make_short4(tobf(o.x), tobf(o.y), tobf(o.z), tobf(o.w));
        ((short4*)(outb + (size_t)n * DHID))[L ^ ((n & 7) << 1)] = ob;
      }
    }
  }
}

extern "C" void kernel_launch(void* const* d_in, const int* in_sizes, int n_in,
                              void* d_out, int out_size, void* d_ws, size_t ws_size,
                              hipStream_t stream) {
  const float* x   = (const float*)d_in[0];
  const int*   ei  = (const int*)d_in[1];
  const float* W1  = (const float*)d_in[2];
  const float* as1 = (const float*)d_in[3];
  const float* ad1 = (const float*)d_in[4];
  const float* b1  = (const float*)d_in[5];
  const float* W2  = (const float*)d_in[6];
  const float* as2 = (const float*)d_in[7];
  const float* ad2 = (const float*)d_in[8];
  const float* b2  = (const float*)d_in[9];

  int N = in_sizes[0] / 128;
  int E = in_sizes[1] / 2;
  const int* srcp = ei;
  const int* dstp = ei + E;

  float* emb  = (float*)d_out;
  float* out2 = emb + (size_t)N * DHID;

  char* w = (char*)d_ws;
  auto alloc = [&](size_t bytes) { char* p = w; w += (bytes + 255) & ~(size_t)255; return p; };
  int NR = ((N + 63) / 64) * 64;
  int* roff = (int*)alloc((size_t)(N + 1) * 4);
  int* csr  = (int*)alloc((size_t)(E + N) * 4);
  int* bsum = (int*)alloc(2048);
  int* bcnt = (int*)alloc(1024);
  char* scr0 = alloc((size_t)NR * 128 * 2);   // bkt, later eb
  short* hb = (short*)alloc((size_t)NR * 64 * 2);
  float* asb = (float*)alloc((size_t)N * 4);
  float* adb = (float*)alloc((size_t)N * 4);
  short* eb = (short*)scr0;       // overlay: layer-2 A input (written by agg1)
  int* bkt  = (int*)scr0;         // overlay: buckets dead before agg1 writes eb

  int nsb = (N + SUBSZ - 1) >> SUBSH;          // sub-buckets
  int cap = E / nsb + 4096;                    // per-sub-bucket capacity (ints)

  int nb = (N + 1023) / 1024;
  int NBLK = (N + 63) / 64;
  int nbkt = (E + EB - 1) / EB;

  hipMemsetAsync(bcnt, 0, (size_t)nsb * 4, stream);
  k_fusedA<<<nbkt + NBLK, 256, 0, stream>>>(srcp, dstp, bkt, bcnt, E, nsb, cap, nbkt,
                                            x, W1, as1, ad1, hb, asb, adb, N);
  k_count<<<nsb, 256, 0, stream>>>(bkt, bcnt, roff, N, cap);
  k_scan_block<<<nb, 256, 0, stream>>>(roff, N, bsum);
  k_scan_mid<<<1, 64, 0, stream>>>(bsum, nb);
  k_scan_add<<<(N + 255) / 256, 256, 0, stream>>>(roff, N, bsum, nb);
  k_place<<<nsb, 256, 0, stream>>>(bkt, bcnt, roff, csr, N, cap);

  k_agg<<<2048, 256, 0, stream>>>(roff, csr, asb, adb, hb, b1, emb, eb, N, 1);
  k_mgemm2<<<NBLK, 256, 0, stream>>>(eb, W2, as2, ad2, hb, asb, adb, N);
  k_agg<<<2048, 256, 0, stream>>>(roff, csr, asb, adb, hb, b2, out2, (short*)nullptr, N, 0);
}

// Round 13
// 173.775 us; speedup vs baseline: 2.0038x; 1.0387x over previous
//
#include <hip/hip_runtime.h>
#include <hip/hip_bf16.h>

#define DHID 64
#define SUBSH 9
#define SUBSZ (1 << SUBSH)     // 512 dst nodes per sub-bucket
#define PCAP 16384             // LDS staging cap (ints) in k_place2
#define EB 2048                // edges per block in bucket pass
typedef __attribute__((ext_vector_type(8))) short short8;
typedef __attribute__((ext_vector_type(4))) float f32x4;

static __device__ __forceinline__ short tobf(float f) {
  __hip_bfloat16 h = __float2bfloat16(f);
  return *reinterpret_cast<short*>(&h);
}

// ---------- fused A: edge bucket partition (blocks < nbkt) || layer-1 MFMA gemm ----------
__global__ __launch_bounds__(256)
void k_fusedA(const int* __restrict__ src, const int* __restrict__ dst,
              int* __restrict__ bkt, int* __restrict__ bcnt,
              int E, int nsb, int cap, int nbkt,
              const float* __restrict__ xf, const float* __restrict__ W1,
              const float* __restrict__ a_s, const float* __restrict__ a_d,
              short* __restrict__ hb, float* __restrict__ asb,
              float* __restrict__ adb, int N) {
  __shared__ int lcnt[256];
  __shared__ int lbase[256];
  __shared__ __align__(16) short ldsB[64 * 128];
  int tid = threadIdx.x;
  if (blockIdx.x < nbkt) {
    // ---- bucket path: single-pass local rank, payload (src<<9)|(d&511) ----
    int c0 = blockIdx.x * EB;
    for (int i = tid; i < nsb; i += 256) lcnt[i] = 0;
    __syncthreads();
    int wloc[8], uloc[8], rloc[8];
    #pragma unroll
    for (int k = 0; k < 8; k++) {
      int i = c0 + tid + k * 256;
      if (i < E) {
        int d = dst[i];
        int w = d >> SUBSH;
        wloc[k] = w;
        uloc[k] = (src[i] << SUBSH) | (d & (SUBSZ - 1));
        rloc[k] = atomicAdd(&lcnt[w], 1);
      } else wloc[k] = -1;
    }
    __syncthreads();
    for (int i = tid; i < nsb; i += 256) lbase[i] = atomicAdd(&bcnt[i], lcnt[i]);
    __syncthreads();
    #pragma unroll
    for (int k = 0; k < 8; k++) {
      int w = wloc[k];
      if (w >= 0) bkt[(size_t)w * cap + lbase[w] + rloc[k]] = uloc[k];
    }
    return;
  }
  // ---- mgemm1 path (K=128): A per-lane fp32->bf16; B = W1 self-converted ----
  int n0 = (blockIdx.x - nbkt) * 64;
  for (int e = tid; e < 128 * 64; e += 256) {
    int k = e >> 6, c = e & 63;
    ldsB[c * 128 + (k ^ ((c & 7) << 3))] = tobf(W1[e]);
  }
  __syncthreads();

  int l = tid & 63, w = tid >> 6;
  int c = l & 15, g = l >> 4;
  f32x4 acc[4];
  #pragma unroll
  for (int t = 0; t < 4; t++) acc[t] = (f32x4){0.f, 0.f, 0.f, 0.f};

  int arow = 16 * w + c;
  int row0 = n0 + arow;
  const float* xr = xf + (size_t)row0 * 128;
  bool okr = row0 < N;
  short8 afr[4];
  #pragma unroll
  for (int s = 0; s < 4; s++) {
    int ke = s * 32 + g * 8;
    float4 u0 = make_float4(0.f, 0.f, 0.f, 0.f), u1 = u0;
    if (okr) { u0 = *(const float4*)(xr + ke); u1 = *(const float4*)(xr + ke + 4); }
    short8 af;
    af[0] = tobf(u0.x); af[1] = tobf(u0.y); af[2] = tobf(u0.z); af[3] = tobf(u0.w);
    af[4] = tobf(u1.x); af[5] = tobf(u1.y); af[6] = tobf(u1.z); af[7] = tobf(u1.w);
    afr[s] = af;
  }
  #pragma unroll
  for (int s = 0; s < 4; s++) {
    int ke = s * 32 + g * 8;
    #pragma unroll
    for (int t = 0; t < 4; t++) {
      int bcol = 16 * t + c;
      short8 bf = *(const short8*)(ldsB + bcol * 128 + (ke ^ ((bcol & 7) << 3)));
      acc[t] = __builtin_amdgcn_mfma_f32_16x16x32_bf16(afr[s], bf, acc[t], 0, 0, 0);
    }
  }
  float av_s[4], av_d[4];
  #pragma unroll
  for (int t = 0; t < 4; t++) { av_s[t] = a_s[16 * t + c]; av_d[t] = a_d[16 * t + c]; }
  #pragma unroll
  for (int q = 0; q < 4; q++) {
    int row = n0 + 16 * w + g * 4 + q;
    bool ok = row < N;
    float rs = 0.f, rd = 0.f;
    #pragma unroll
    for (int t = 0; t < 4; t++) {
      float v = acc[t][q];
      if (ok) hb[(size_t)row * 64 + 16 * t + c] = tobf(v);
      rs += v * av_s[t]; rd += v * av_d[t];
    }
    #pragma unroll
    for (int off = 1; off < 16; off <<= 1) {
      rs += __shfl_xor(rs, off, 64);
      rd += __shfl_xor(rd, off, 64);
    }
    if (ok && c == 0) { asb[row] = rs; adb[row] = rd; }
  }
}

// ---------- merged count + scan + place (one block per sub-bucket) ----------
// Derives the global csr base by scanning all sub-bucket totals in-block,
// histograms its bucket, scans 512 per-dst counts in LDS, writes roff
// coalesced, then counting-sort places and streams the csr span out.
// csr stores BYTE offsets (src*128).
__global__ __launch_bounds__(256)
void k_place2(const int* __restrict__ bkt, const int* __restrict__ bcnt,
              int* __restrict__ roff, int* __restrict__ csr,
              int N, int nsb, int cap) {
  __shared__ int scanbuf[256];
  __shared__ int h[SUBSZ];
  __shared__ int roff_l[SUBSZ + 1];
  __shared__ int lcnt[SUBSZ];
  __shared__ int stage[PCAP];
  __shared__ int sbase;
  int sb = blockIdx.x, tid = threadIdx.x;
  int d0 = sb << SUBSH;
  int nn = min(N - d0, SUBSZ);

  // global base = exclusive scan over (bcnt[t] + nodes_in_subbucket(t)); nsb<=256
  int tot = 0;
  if (tid < nsb) tot = bcnt[tid] + min(N - (tid << SUBSH), SUBSZ);
  scanbuf[tid] = tot; __syncthreads();
  for (int off = 1; off < 256; off <<= 1) {
    int t = (tid >= off) ? scanbuf[tid - off] : 0;
    __syncthreads(); scanbuf[tid] += t; __syncthreads();
  }
  if (tid == sb) sbase = scanbuf[tid] - tot;
  __syncthreads();

  // per-dst histogram (init 1: self-loop)
  for (int j = tid; j < SUBSZ; j += 256) { h[j] = 1; lcnt[j] = 0; }
  __syncthreads();
  int nE = bcnt[sb];
  const int* b = bkt + (size_t)sb * cap;
  for (int i = tid; i < nE; i += 256) atomicAdd(&h[b[i] & (SUBSZ - 1)], 1);
  __syncthreads();

  // 512-wide exclusive scan (pairs per thread)
  int a0 = h[2 * tid], a1 = h[2 * tid + 1];
  int s = a0 + a1;
  scanbuf[tid] = s; __syncthreads();
  for (int off = 1; off < 256; off <<= 1) {
    int t = (tid >= off) ? scanbuf[tid - off] : 0;
    __syncthreads(); scanbuf[tid] += t; __syncthreads();
  }
  int excl = sbase + scanbuf[tid] - s;
  roff_l[2 * tid] = excl;
  roff_l[2 * tid + 1] = excl + a0;
  if (tid == 255) roff_l[SUBSZ] = sbase + scanbuf[255];
  __syncthreads();

  // write roff (coalesced)
  for (int j = tid; j < nn; j += 256) roff[d0 + j] = roff_l[j];
  if (d0 + nn == N && tid == 0) roff[N] = roff_l[nn];

  // place
  int base0 = roff_l[0];
  int span = roff_l[nn] - base0;
  if (span <= PCAP) {
    for (int d = tid; d < nn; d += 256) stage[roff_l[d] - base0] = (d0 + d) << 7; // self-loop
    for (int i = tid; i < nE; i += 256) {
      int u = b[i];
      int dl = u & (SUBSZ - 1);
      int rk = 1 + atomicAdd(&lcnt[dl], 1);
      stage[roff_l[dl] - base0 + rk] = (u >> SUBSH) << 7;
    }
    __syncthreads();
    for (int j = tid; j < span; j += 256) csr[base0 + j] = stage[j];
  } else {  // correctness fallback (never for random graphs)
    for (int d = tid; d < nn; d += 256) csr[roff_l[d]] = (d0 + d) << 7;
    for (int i = tid; i < nE; i += 256) {
      int u = b[i];
      int dl = u & (SUBSZ - 1);
      int rk = 1 + atomicAdd(&lcnt[dl], 1);
      csr[roff_l[dl] + rk] = (u >> SUBSH) << 7;
    }
  }
}

// ---------- layer-2 MFMA gemm ----------
__global__ __launch_bounds__(256)
void k_mgemm2(const short* __restrict__ eb, const float* __restrict__ W2,
              const float* __restrict__ a_s, const float* __restrict__ a_d,
              short* __restrict__ hb, float* __restrict__ asb,
              float* __restrict__ adb, int N) {
  __shared__ __align__(16) short lds[64 * 64 * 2];   // A (8KB) + B (8KB)
  int tid = threadIdx.x;
  int n0 = blockIdx.x * 64;
  const char* ga = (const char*)eb + (size_t)n0 * 128;
  #pragma unroll
  for (int j = 0; j < 2; j++) {
    int d = j * 4096 + tid * 16;
    __builtin_amdgcn_global_load_lds(
        (__attribute__((address_space(1))) const void*)(ga + d),
        (__attribute__((address_space(3))) void*)((char*)lds + d), 16, 0, 0);
  }
  short* B = lds + 64 * 64;
  for (int e = tid; e < 64 * 64; e += 256) {
    int k = e >> 6, c = e & 63;
    B[c * 64 + (k ^ ((c & 7) << 3))] = tobf(W2[e]);
  }
  __syncthreads();

  int l = tid & 63, w = tid >> 6;
  int c = l & 15, g = l >> 4;
  const short* A = lds;
  f32x4 acc[4];
  #pragma unroll
  for (int t = 0; t < 4; t++) acc[t] = (f32x4){0.f, 0.f, 0.f, 0.f};
  int arow = 16 * w + c;
  #pragma unroll
  for (int s = 0; s < 2; s++) {
    int ke = s * 32 + g * 8;
    short8 af = *(const short8*)(A + arow * 64 + (ke ^ ((arow & 7) << 3)));
    #pragma unroll
    for (int t = 0; t < 4; t++) {
      int bcol = 16 * t + c;
      short8 bf = *(const short8*)(B + bcol * 64 + (ke ^ ((bcol & 7) << 3)));
      acc[t] = __builtin_amdgcn_mfma_f32_16x16x32_bf16(af, bf, acc[t], 0, 0, 0);
    }
  }
  float av_s[4], av_d[4];
  #pragma unroll
  for (int t = 0; t < 4; t++) { av_s[t] = a_s[16 * t + c]; av_d[t] = a_d[16 * t + c]; }
  #pragma unroll
  for (int q = 0; q < 4; q++) {
    int row = n0 + 16 * w + g * 4 + q;
    bool ok = row < N;
    float rs = 0.f, rd = 0.f;
    #pragma unroll
    for (int t = 0; t < 4; t++) {
      float v = acc[t][q];
      if (ok) hb[(size_t)row * 64 + 16 * t + c] = tobf(v);
      rs += v * av_s[t]; rd += v * av_d[t];
    }
    #pragma unroll
    for (int off = 1; off < 16; off <<= 1) {
      rs += __shfl_xor(rs, off, 64);
      rd += __shfl_xor(rd, off, 64);
    }
    if (ok && c == 0) { asb[row] = rs; adb[row] = rd; }
  }
}

// ---------- sparse: fused softmax + aggregation ----------
// 16 lanes per h row (4 bf16 cols/lane via dwordx2), 4 edges per wave-op;
// weights/offsets broadcast to 16-lane groups via ds_bpermute; unroll 8
// keeps 8 row-gathers in flight.
__global__ void k_agg(const int* __restrict__ roff, const int* __restrict__ csr,
                      const float* __restrict__ asb, const float* __restrict__ adb,
                      const short* __restrict__ hb, const float* __restrict__ b,
                      float* __restrict__ out, short* __restrict__ outb,
                      int N, int relu) {
  const char* hbase = (const char*)hb;
  int lane = threadIdx.x & 63;
  int colb = (lane & 15) * 8;            // byte offset of this lane's 4 cols
  int L = lane & 15;
  int wid = blockIdx.x * (blockDim.x >> 6) + (threadIdx.x >> 6);
  int nw = gridDim.x * (blockDim.x >> 6);
  float4 bv4 = ((const float4*)b)[L];
  for (int n = wid; n < N; n += nw) {
    int r0 = roff[n], r1 = roff[n + 1];
    float adn = adb[n];
    float a0 = 0.f, a1 = 0.f, a2 = 0.f, a3 = 0.f, denl = 0.f;
    for (int base = r0; base < r1; base += 64) {
      int cnt = min(64, r1 - base);
      int s128 = 0; float e = 0.f;
      if (lane < cnt) {
        s128 = csr[base + lane];          // byte offset src*128
        float l = asb[s128 >> 7] + adn;
        l = fmaxf(l, 0.2f * l);
        e = __expf(l);
      }
      denl += e;
      int cntUp = (cnt + 3) & ~3;
      int addrv = (lane >> 4) << 2;       // bpermute byte-addr: group g -> edge j+g
      #pragma unroll 8
      for (int j = 0; j < cntUp; j += 4) {
        int sofs = __builtin_amdgcn_ds_bpermute(addrv, s128);
        int ewi  = __builtin_amdgcn_ds_bpermute(addrv, (int)__float_as_uint(e));
        addrv += 16;
        float ew = __uint_as_float((unsigned)ewi);
        uint2 u = *(const uint2*)(hbase + (unsigned)(sofs + colb));
        a0 = fmaf(__uint_as_float(u.x << 16), ew, a0);
        a1 = fmaf(__uint_as_float(u.x & 0xFFFF0000u), ew, a1);
        a2 = fmaf(__uint_as_float(u.y << 16), ew, a2);
        a3 = fmaf(__uint_as_float(u.y & 0xFFFF0000u), ew, a3);
      }
    }
    #pragma unroll
    for (int off = 16; off <= 32; off <<= 1) {
      a0 += __shfl_xor(a0, off, 64); a1 += __shfl_xor(a1, off, 64);
      a2 += __shfl_xor(a2, off, 64); a3 += __shfl_xor(a3, off, 64);
    }
    float den = denl;
    #pragma unroll
    for (int off = 32; off; off >>= 1) den += __shfl_xor(den, off, 64);
    float inv = 1.f / (den + 1e-16f);
    if (lane < 16) {
      float4 o;
      o.x = fmaf(a0, inv, bv4.x); o.y = fmaf(a1, inv, bv4.y);
      o.z = fmaf(a2, inv, bv4.z); o.w = fmaf(a3, inv, bv4.w);
      if (relu) {
        o.x = fmaxf(o.x, 0.f); o.y = fmaxf(o.y, 0.f);
        o.z = fmaxf(o.z, 0.f); o.w = fmaxf(o.w, 0.f);
      }
      ((float4*)(out + (size_t)n * DHID))[L] = o;
      if (outb) {
        // col swizzle c^=((n&7)<<3) touches only bits 3-5 -> short4 grain moves
        // as a unit: L' = L ^ ((n&7)<<1)
        short4 ob = make_short4(tobf(o.x), tobf(o.y), tobf(o.z), tobf(o.w));
        ((short4*)(outb + (size_t)n * DHID))[L ^ ((n & 7) << 1)] = ob;
      }
    }
  }
}

extern "C" void kernel_launch(void* const* d_in, const int* in_sizes, int n_in,
                              void* d_out, int out_size, void* d_ws, size_t ws_size,
                              hipStream_t stream) {
  const float* x   = (const float*)d_in[0];
  const int*   ei  = (const int*)d_in[1];
  const float* W1  = (const float*)d_in[2];
  const float* as1 = (const float*)d_in[3];
  const float* ad1 = (const float*)d_in[4];
  const float* b1  = (const float*)d_in[5];
  const float* W2  = (const float*)d_in[6];
  const float* as2 = (const float*)d_in[7];
  const float* ad2 = (const float*)d_in[8];
  const float* b2  = (const float*)d_in[9];

  int N = in_sizes[0] / 128;
  int E = in_sizes[1] / 2;
  const int* srcp = ei;
  const int* dstp = ei + E;

  float* emb  = (float*)d_out;
  float* out2 = emb + (size_t)N * DHID;

  char* w = (char*)d_ws;
  auto alloc = [&](size_t bytes) { char* p = w; w += (bytes + 255) & ~(size_t)255; return p; };
  int NR = ((N + 63) / 64) * 64;
  int* roff = (int*)alloc((size_t)(N + 1) * 4);
  int* csr  = (int*)alloc((size_t)(E + N) * 4);
  int* bcnt = (int*)alloc(1024);
  char* scr0 = alloc((size_t)NR * 128 * 2);   // bkt, later eb
  short* hb = (short*)alloc((size_t)NR * 64 * 2);
  float* asb = (float*)alloc((size_t)N * 4);
  float* adb = (float*)alloc((size_t)N * 4);
  short* eb = (short*)scr0;       // overlay: layer-2 A input (written by agg1)
  int* bkt  = (int*)scr0;         // overlay: buckets dead before agg1 writes eb

  int nsb = (N + SUBSZ - 1) >> SUBSH;          // sub-buckets (<=256 assumed)
  int cap = E / nsb + 4096;                    // per-sub-bucket capacity (ints)

  int NBLK = (N + 63) / 64;
  int nbkt = (E + EB - 1) / EB;

  hipMemsetAsync(bcnt, 0, (size_t)nsb * 4, stream);
  k_fusedA<<<nbkt + NBLK, 256, 0, stream>>>(srcp, dstp, bkt, bcnt, E, nsb, cap, nbkt,
                                            x, W1, as1, ad1, hb, asb, adb, N);
  k_place2<<<nsb, 256, 0, stream>>>(bkt, bcnt, roff, csr, N, nsb, cap);

  k_agg<<<2048, 256, 0, stream>>>(roff, csr, asb, adb, hb, b1, emb, eb, N, 1);
  k_mgemm2<<<NBLK, 256, 0, stream>>>(eb, W2, as2, ad2, hb, asb, adb, N);
  k_agg<<<2048, 256, 0, stream>>>(roff, csr, asb, adb, hb, b2, out2, (short*)nullptr, N, 0);
}

// Round 14
// 163.993 us; speedup vs baseline: 2.1233x; 1.0596x over previous
//
#include <hip/hip_runtime.h>
#include <hip/hip_bf16.h>

#define DHID 64
#define SUBSH 9
#define SUBSZ (1 << SUBSH)     // 512 dst nodes per sub-bucket
#define PCAP 16384             // LDS staging cap (ints) in k_place2
#define EB 2048                // edges per block in bucket pass
typedef __attribute__((ext_vector_type(8))) short short8;
typedef __attribute__((ext_vector_type(4))) float f32x4;

static __device__ __forceinline__ short tobf(float f) {
  __hip_bfloat16 h = __float2bfloat16(f);
  return *reinterpret_cast<short*>(&h);
}

// ---------- fused A: edge bucket partition (blocks < nbkt) || layer-1 MFMA gemm ----------
__global__ __launch_bounds__(256)
void k_fusedA(const int* __restrict__ src, const int* __restrict__ dst,
              int* __restrict__ bkt, int* __restrict__ bcnt,
              int E, int nsb, int cap, int nbkt,
              const float* __restrict__ xf, const float* __restrict__ W1,
              const float* __restrict__ a_s, const float* __restrict__ a_d,
              short* __restrict__ hb, float* __restrict__ asb,
              float* __restrict__ adb, int N) {
  __shared__ int lcnt[256];
  __shared__ int lbase[256];
  __shared__ __align__(16) short ldsB[64 * 128];
  int tid = threadIdx.x;
  if (blockIdx.x < nbkt) {
    // ---- bucket path: single-pass local rank, payload (src<<9)|(d&511) ----
    int c0 = blockIdx.x * EB;
    for (int i = tid; i < nsb; i += 256) lcnt[i] = 0;
    __syncthreads();
    int wloc[8], uloc[8], rloc[8];
    #pragma unroll
    for (int k = 0; k < 8; k++) {
      int i = c0 + tid + k * 256;
      if (i < E) {
        int d = dst[i];
        int w = d >> SUBSH;
        wloc[k] = w;
        uloc[k] = (src[i] << SUBSH) | (d & (SUBSZ - 1));
        rloc[k] = atomicAdd(&lcnt[w], 1);
      } else wloc[k] = -1;
    }
    __syncthreads();
    for (int i = tid; i < nsb; i += 256) lbase[i] = atomicAdd(&bcnt[i], lcnt[i]);
    __syncthreads();
    #pragma unroll
    for (int k = 0; k < 8; k++) {
      int w = wloc[k];
      if (w >= 0) bkt[(size_t)w * cap + lbase[w] + rloc[k]] = uloc[k];
    }
    return;
  }
  // ---- mgemm1 path (K=128): A per-lane fp32->bf16; B = W1 self-converted ----
  int n0 = (blockIdx.x - nbkt) * 64;
  for (int e = tid; e < 128 * 64; e += 256) {
    int k = e >> 6, c = e & 63;
    ldsB[c * 128 + (k ^ ((c & 7) << 3))] = tobf(W1[e]);
  }
  __syncthreads();

  int l = tid & 63, w = tid >> 6;
  int c = l & 15, g = l >> 4;
  f32x4 acc[4];
  #pragma unroll
  for (int t = 0; t < 4; t++) acc[t] = (f32x4){0.f, 0.f, 0.f, 0.f};

  int arow = 16 * w + c;
  int row0 = n0 + arow;
  const float* xr = xf + (size_t)row0 * 128;
  bool okr = row0 < N;
  short8 afr[4];
  #pragma unroll
  for (int s = 0; s < 4; s++) {
    int ke = s * 32 + g * 8;
    float4 u0 = make_float4(0.f, 0.f, 0.f, 0.f), u1 = u0;
    if (okr) { u0 = *(const float4*)(xr + ke); u1 = *(const float4*)(xr + ke + 4); }
    short8 af;
    af[0] = tobf(u0.x); af[1] = tobf(u0.y); af[2] = tobf(u0.z); af[3] = tobf(u0.w);
    af[4] = tobf(u1.x); af[5] = tobf(u1.y); af[6] = tobf(u1.z); af[7] = tobf(u1.w);
    afr[s] = af;
  }
  #pragma unroll
  for (int s = 0; s < 4; s++) {
    int ke = s * 32 + g * 8;
    #pragma unroll
    for (int t = 0; t < 4; t++) {
      int bcol = 16 * t + c;
      short8 bf = *(const short8*)(ldsB + bcol * 128 + (ke ^ ((bcol & 7) << 3)));
      acc[t] = __builtin_amdgcn_mfma_f32_16x16x32_bf16(afr[s], bf, acc[t], 0, 0, 0);
    }
  }
  float av_s[4], av_d[4];
  #pragma unroll
  for (int t = 0; t < 4; t++) { av_s[t] = a_s[16 * t + c]; av_d[t] = a_d[16 * t + c]; }
  #pragma unroll
  for (int q = 0; q < 4; q++) {
    int row = n0 + 16 * w + g * 4 + q;
    bool ok = row < N;
    float rs = 0.f, rd = 0.f;
    #pragma unroll
    for (int t = 0; t < 4; t++) {
      float v = acc[t][q];
      if (ok) hb[(size_t)row * 64 + 16 * t + c] = tobf(v);
      rs += v * av_s[t]; rd += v * av_d[t];
    }
    #pragma unroll
    for (int off = 1; off < 16; off <<= 1) {
      rs += __shfl_xor(rs, off, 64);
      rd += __shfl_xor(rd, off, 64);
    }
    if (ok && c == 0) { asb[row] = rs; adb[row] = rd; }
  }
}

// ---------- merged count + scan + place (one block per sub-bucket) ----------
__global__ __launch_bounds__(256)
void k_place2(const int* __restrict__ bkt, const int* __restrict__ bcnt,
              int* __restrict__ roff, int* __restrict__ csr,
              int N, int nsb, int cap) {
  __shared__ int scanbuf[256];
  __shared__ int h[SUBSZ];
  __shared__ int roff_l[SUBSZ + 1];
  __shared__ int lcnt[SUBSZ];
  __shared__ int stage[PCAP];
  __shared__ int sbase;
  int sb = blockIdx.x, tid = threadIdx.x;
  int d0 = sb << SUBSH;
  int nn = min(N - d0, SUBSZ);

  // global base = exclusive scan over (bcnt[t] + nodes_in_subbucket(t)); nsb<=256
  int tot = 0;
  if (tid < nsb) tot = bcnt[tid] + min(N - (tid << SUBSH), SUBSZ);
  scanbuf[tid] = tot; __syncthreads();
  for (int off = 1; off < 256; off <<= 1) {
    int t = (tid >= off) ? scanbuf[tid - off] : 0;
    __syncthreads(); scanbuf[tid] += t; __syncthreads();
  }
  if (tid == sb) sbase = scanbuf[tid] - tot;
  __syncthreads();

  // per-dst histogram (init 1: self-loop)
  for (int j = tid; j < SUBSZ; j += 256) { h[j] = 1; lcnt[j] = 0; }
  __syncthreads();
  int nE = bcnt[sb];
  const int* b = bkt + (size_t)sb * cap;
  for (int i = tid; i < nE; i += 256) atomicAdd(&h[b[i] & (SUBSZ - 1)], 1);
  __syncthreads();

  // 512-wide exclusive scan (pairs per thread)
  int a0 = h[2 * tid], a1 = h[2 * tid + 1];
  int s = a0 + a1;
  scanbuf[tid] = s; __syncthreads();
  for (int off = 1; off < 256; off <<= 1) {
    int t = (tid >= off) ? scanbuf[tid - off] : 0;
    __syncthreads(); scanbuf[tid] += t; __syncthreads();
  }
  int excl = sbase + scanbuf[tid] - s;
  roff_l[2 * tid] = excl;
  roff_l[2 * tid + 1] = excl + a0;
  if (tid == 255) roff_l[SUBSZ] = sbase + scanbuf[255];
  __syncthreads();

  for (int j = tid; j < nn; j += 256) roff[d0 + j] = roff_l[j];
  if (d0 + nn == N && tid == 0) roff[N] = roff_l[nn];

  int base0 = roff_l[0];
  int span = roff_l[nn] - base0;
  if (span <= PCAP) {
    for (int d = tid; d < nn; d += 256) stage[roff_l[d] - base0] = (d0 + d) << 7; // self-loop
    for (int i = tid; i < nE; i += 256) {
      int u = b[i];
      int dl = u & (SUBSZ - 1);
      int rk = 1 + atomicAdd(&lcnt[dl], 1);
      stage[roff_l[dl] - base0 + rk] = (u >> SUBSH) << 7;
    }
    __syncthreads();
    for (int j = tid; j < span; j += 256) csr[base0 + j] = stage[j];
  } else {  // correctness fallback (never for random graphs)
    for (int d = tid; d < nn; d += 256) csr[roff_l[d]] = (d0 + d) << 7;
    for (int i = tid; i < nE; i += 256) {
      int u = b[i];
      int dl = u & (SUBSZ - 1);
      int rk = 1 + atomicAdd(&lcnt[dl], 1);
      csr[roff_l[dl] + rk] = (u >> SUBSH) << 7;
    }
  }
}

// ---------- layer-2 MFMA gemm ----------
__global__ __launch_bounds__(256)
void k_mgemm2(const short* __restrict__ eb, const float* __restrict__ W2,
              const float* __restrict__ a_s, const float* __restrict__ a_d,
              short* __restrict__ hb, float* __restrict__ asb,
              float* __restrict__ adb, int N) {
  __shared__ __align__(16) short lds[64 * 64 * 2];   // A (8KB) + B (8KB)
  int tid = threadIdx.x;
  int n0 = blockIdx.x * 64;
  const char* ga = (const char*)eb + (size_t)n0 * 128;
  #pragma unroll
  for (int j = 0; j < 2; j++) {
    int d = j * 4096 + tid * 16;
    __builtin_amdgcn_global_load_lds(
        (__attribute__((address_space(1))) const void*)(ga + d),
        (__attribute__((address_space(3))) void*)((char*)lds + d), 16, 0, 0);
  }
  short* B = lds + 64 * 64;
  for (int e = tid; e < 64 * 64; e += 256) {
    int k = e >> 6, c = e & 63;
    B[c * 64 + (k ^ ((c & 7) << 3))] = tobf(W2[e]);
  }
  __syncthreads();

  int l = tid & 63, w = tid >> 6;
  int c = l & 15, g = l >> 4;
  const short* A = lds;
  f32x4 acc[4];
  #pragma unroll
  for (int t = 0; t < 4; t++) acc[t] = (f32x4){0.f, 0.f, 0.f, 0.f};
  int arow = 16 * w + c;
  #pragma unroll
  for (int s = 0; s < 2; s++) {
    int ke = s * 32 + g * 8;
    short8 af = *(const short8*)(A + arow * 64 + (ke ^ ((arow & 7) << 3)));
    #pragma unroll
    for (int t = 0; t < 4; t++) {
      int bcol = 16 * t + c;
      short8 bf = *(const short8*)(B + bcol * 64 + (ke ^ ((bcol & 7) << 3)));
      acc[t] = __builtin_amdgcn_mfma_f32_16x16x32_bf16(af, bf, acc[t], 0, 0, 0);
    }
  }
  float av_s[4], av_d[4];
  #pragma unroll
  for (int t = 0; t < 4; t++) { av_s[t] = a_s[16 * t + c]; av_d[t] = a_d[16 * t + c]; }
  #pragma unroll
  for (int q = 0; q < 4; q++) {
    int row = n0 + 16 * w + g * 4 + q;
    bool ok = row < N;
    float rs = 0.f, rd = 0.f;
    #pragma unroll
    for (int t = 0; t < 4; t++) {
      float v = acc[t][q];
      if (ok) hb[(size_t)row * 64 + 16 * t + c] = tobf(v);
      rs += v * av_s[t]; rd += v * av_d[t];
    }
    #pragma unroll
    for (int off = 1; off < 16; off <<= 1) {
      rs += __shfl_xor(rs, off, 64);
      rd += __shfl_xor(rd, off, 64);
    }
    if (ok && c == 0) { asb[row] = rs; adb[row] = rd; }
  }
}

// ---------- sparse: fused softmax + aggregation, 3-stage node pipeline ----------
// Per-node front chain (roff -> csr -> asb -> exp) is prefetched 1-2 nodes
// ahead so its ~600cy latency hides under the current node's gather loop.
__global__ void k_agg(const int* __restrict__ roff, const int* __restrict__ csr,
                      const float* __restrict__ asb, const float* __restrict__ adb,
                      const short* __restrict__ hb, const float* __restrict__ b,
                      float* __restrict__ out, short* __restrict__ outb,
                      int N, int relu) {
  const char* hbase = (const char*)hb;
  int lane = threadIdx.x & 63;
  int colb = (lane & 15) * 8;            // byte offset of this lane's 4 cols
  int L = lane & 15;
  int wid = blockIdx.x * (blockDim.x >> 6) + (threadIdx.x >> 6);
  int nw = gridDim.x * (blockDim.x >> 6);
  float4 bv4 = ((const float4*)b)[L];

  // pipeline state: current node (r0c,r1c,adc,sc,avc), next node (r0n,r1n,adn,sn)
  int r0c = 0, r1c = 0, sc = 0, r0n = 0, r1n = 0, sn = 0;
  float adc = 0.f, avc = 0.f, adn = 0.f;
  if (wid < N) {
    r0c = roff[wid]; r1c = roff[wid + 1]; adc = adb[wid];
    if (lane < min(64, r1c - r0c)) sc = csr[r0c + lane];
    avc = asb[sc >> 7];
  }
  if (wid + nw < N) {
    r0n = roff[wid + nw]; r1n = roff[wid + nw + 1]; adn = adb[wid + nw];
    if (lane < min(64, r1n - r0n)) sn = csr[r0n + lane];
  }

  for (int n = wid; n < N; n += nw) {
    // e for current node: VALU only (avc prefetched)
    int cnt0 = min(64, r1c - r0c);
    float e = 0.f;
    if (lane < cnt0) {
      float l = avc + adc;
      l = fmaxf(l, 0.2f * l);
      e = __expf(l);
    }
    // issue loads for n+2nw (roff/adb) and n+nw (asb) before the gather loop
    int n2 = n + 2 * nw;
    int r02 = 0, r12 = 0; float ad2 = 0.f;
    if (n2 < N) { r02 = roff[n2]; r12 = roff[n2 + 1]; ad2 = adb[n2]; }
    float avn = asb[sn >> 7];          // sn=0 when invalid -> harmless read

    // gather chunk 0
    float a0 = 0.f, a1 = 0.f, a2 = 0.f, a3 = 0.f, denl = e;
    {
      int cntUp = (cnt0 + 3) & ~3;
      int addrv = (lane >> 4) << 2;     // bpermute byte-addr: group g -> edge j+g
      #pragma unroll 4
      for (int j = 0; j < cntUp; j += 4) {
        int sofs = __builtin_amdgcn_ds_bpermute(addrv, sc);
        int ewi  = __builtin_amdgcn_ds_bpermute(addrv, (int)__float_as_uint(e));
        addrv += 16;
        float ew = __uint_as_float((unsigned)ewi);
        uint2 u = *(const uint2*)(hbase + (unsigned)(sofs + colb));
        a0 = fmaf(__uint_as_float(u.x << 16), ew, a0);
        a1 = fmaf(__uint_as_float(u.x & 0xFFFF0000u), ew, a1);
        a2 = fmaf(__uint_as_float(u.y << 16), ew, a2);
        a3 = fmaf(__uint_as_float(u.y & 0xFFFF0000u), ew, a3);
      }
    }
    // rare extra chunks (degree > 63): serial path
    for (int base = r0c + 64; base < r1c; base += 64) {
      int cnt = min(64, r1c - base);
      int s128 = 0; float e2 = 0.f;
      if (lane < cnt) {
        s128 = csr[base + lane];
        float l = asb[s128 >> 7] + adc;
        l = fmaxf(l, 0.2f * l);
        e2 = __expf(l);
      }
      denl += e2;
      int cntUp = (cnt + 3) & ~3;
      int addrv = (lane >> 4) << 2;
      for (int j = 0; j < cntUp; j += 4) {
        int sofs = __builtin_amdgcn_ds_bpermute(addrv, s128);
        int ewi  = __builtin_amdgcn_ds_bpermute(addrv, (int)__float_as_uint(e2));
        addrv += 16;
        float ew = __uint_as_float((unsigned)ewi);
        uint2 u = *(const uint2*)(hbase + (unsigned)(sofs + colb));
        a0 = fmaf(__uint_as_float(u.x << 16), ew, a0);
        a1 = fmaf(__uint_as_float(u.x & 0xFFFF0000u), ew, a1);
        a2 = fmaf(__uint_as_float(u.y << 16), ew, a2);
        a3 = fmaf(__uint_as_float(u.y & 0xFFFF0000u), ew, a3);
      }
    }
    // epilogue: cross-group reduce + write
    #pragma unroll
    for (int off = 16; off <= 32; off <<= 1) {
      a0 += __shfl_xor(a0, off, 64); a1 += __shfl_xor(a1, off, 64);
      a2 += __shfl_xor(a2, off, 64); a3 += __shfl_xor(a3, off, 64);
    }
    float den = denl;
    #pragma unroll
    for (int off = 32; off; off >>= 1) den += __shfl_xor(den, off, 64);
    float inv = 1.f / (den + 1e-16f);
    if (lane < 16) {
      float4 o;
      o.x = fmaf(a0, inv, bv4.x); o.y = fmaf(a1, inv, bv4.y);
      o.z = fmaf(a2, inv, bv4.z); o.w = fmaf(a3, inv, bv4.w);
      if (relu) {
        o.x = fmaxf(o.x, 0.f); o.y = fmaxf(o.y, 0.f);
        o.z = fmaxf(o.z, 0.f); o.w = fmaxf(o.w, 0.f);
      }
      ((float4*)(out + (size_t)n * DHID))[L] = o;
      if (outb) {
        // col swizzle c^=((n&7)<<3) touches only bits 3-5 -> short4 grain moves
        // as a unit: L' = L ^ ((n&7)<<1)
        short4 ob = make_short4(tobf(o.x), tobf(o.y), tobf(o.z), tobf(o.w));
        ((short4*)(outb + (size_t)n * DHID))[L ^ ((n & 7) << 1)] = ob;
      }
    }
    // rotate pipeline; csr for n+2nw (r02 arrived during the gather loop)
    r0c = r0n; r1c = r1n; adc = adn; sc = sn; avc = avn;
    r0n = r02; r1n = r12; adn = ad2;
    sn = 0;
    if (n2 < N && lane < min(64, r1n - r0n)) sn = csr[r0n + lane];
  }
}

extern "C" void kernel_launch(void* const* d_in, const int* in_sizes, int n_in,
                              void* d_out, int out_size, void* d_ws, size_t ws_size,
                              hipStream_t stream) {
  const float* x   = (const float*)d_in[0];
  const int*   ei  = (const int*)d_in[1];
  const float* W1  = (const float*)d_in[2];
  const float* as1 = (const float*)d_in[3];
  const float* ad1 = (const float*)d_in[4];
  const float* b1  = (const float*)d_in[5];
  const float* W2  = (const float*)d_in[6];
  const float* as2 = (const float*)d_in[7];
  const float* ad2 = (const float*)d_in[8];
  const float* b2  = (const float*)d_in[9];

  int N = in_sizes[0] / 128;
  int E = in_sizes[1] / 2;
  const int* srcp = ei;
  const int* dstp = ei + E;

  float* emb  = (float*)d_out;
  float* out2 = emb + (size_t)N * DHID;

  char* w = (char*)d_ws;
  auto alloc = [&](size_t bytes) { char* p = w; w += (bytes + 255) & ~(size_t)255; return p; };
  int NR = ((N + 63) / 64) * 64;
  int* roff = (int*)alloc((size_t)(N + 1) * 4);
  int* csr  = (int*)alloc((size_t)(E + N) * 4);
  int* bcnt = (int*)alloc(1024);
  char* scr0 = alloc((size_t)NR * 128 * 2);   // bkt, later eb
  short* hb = (short*)alloc((size_t)NR * 64 * 2);
  float* asb = (float*)alloc((size_t)N * 4);
  float* adb = (float*)alloc((size_t)N * 4);
  short* eb = (short*)scr0;       // overlay: layer-2 A input (written by agg1)
  int* bkt  = (int*)scr0;         // overlay: buckets dead before agg1 writes eb

  int nsb = (N + SUBSZ - 1) >> SUBSH;          // sub-buckets (<=256 assumed)
  int cap = E / nsb + 4096;                    // per-sub-bucket capacity (ints)

  int NBLK = (N + 63) / 64;
  int nbkt = (E + EB - 1) / EB;

  hipMemsetAsync(bcnt, 0, (size_t)nsb * 4, stream);
  k_fusedA<<<nbkt + NBLK, 256, 0, stream>>>(srcp, dstp, bkt, bcnt, E, nsb, cap, nbkt,
                                            x, W1, as1, ad1, hb, asb, adb, N);
  k_place2<<<nsb, 256, 0, stream>>>(bkt, bcnt, roff, csr, N, nsb, cap);

  k_agg<<<2048, 256, 0, stream>>>(roff, csr, asb, adb, hb, b1, emb, eb, N, 1);
  k_mgemm2<<<NBLK, 256, 0, stream>>>(eb, W2, as2, ad2, hb, asb, adb, N);
  k_agg<<<2048, 256, 0, stream>>>(roff, csr, asb, adb, hb, b2, out2, (short*)nullptr, N, 0);
}